// Round 2
// baseline (16705.396 us; speedup 1.0000x reference)
//
#include <hip/hip_runtime.h>
#include <math.h>

// ---- problem constants ----
#define Bn 32
#define Sn 197
#define Dn 768
#define Hn 12
#define DHn 64
#define Fn 3072
#define Ln 12
#define NPATCH 196
#define NCLSn 1000
#define MTOK (Bn * Sn)   // 6304
#define MPAD 6400        // MTOK padded to multiple of 128 (gemm128 staging reads)

typedef __attribute__((ext_vector_type(8))) short short8;
typedef __attribute__((ext_vector_type(4))) float f32x4;

__device__ __forceinline__ unsigned short f2bf(float f) {
  union { float f; unsigned int u; } v; v.f = f;
  unsigned int r = v.u + 0x7fffu + ((v.u >> 16) & 1u);
  return (unsigned short)(r >> 16);
}
__device__ __forceinline__ float bf2f(unsigned short h) {
  union { unsigned int u; float f; } v; v.u = ((unsigned int)h) << 16;
  return v.f;
}

// direct HBM -> LDS DMA, 16B per lane (dest = wave-uniform base + lane*16)
__device__ __forceinline__ void gload16(const unsigned short* g, unsigned short* l) {
  __builtin_amdgcn_global_load_lds(
      (const __attribute__((address_space(1))) unsigned int*)g,
      (__attribute__((address_space(3))) unsigned int*)l, 16, 0, 0);
}

// ---- transpose + cast fp32[rows][cols] -> bf16[cols][rows] ----
__global__ __launch_bounds__(256) void transpose_cast(
    const float* __restrict__ in, unsigned short* __restrict__ out,
    int rows, int cols) {
  __shared__ float tile[32][33];
  int c0 = blockIdx.x * 32, r0 = blockIdx.y * 32;
  int tx = threadIdx.x, ty = threadIdx.y;
  for (int i = 0; i < 32; i += 8) {
    int r = r0 + ty + i, c = c0 + tx;
    tile[ty + i][tx] = (r < rows && c < cols) ? in[(size_t)r * cols + c] : 0.f;
  }
  __syncthreads();
  for (int i = 0; i < 32; i += 8) {
    int c = c0 + ty + i, r = r0 + tx;
    if (c < cols && r < rows)
      out[(size_t)c * rows + r] = f2bf(tile[tx][ty + i]);
  }
}

// ---- plain cast fp32 -> bf16 ----
__global__ __launch_bounds__(256) void cast_bf(
    const float* __restrict__ in, unsigned short* __restrict__ out, int n) {
  int i = blockIdx.x * 256 + threadIdx.x;
  if (i < n) out[i] = f2bf(in[i]);
}

// ---- im2col: X[B,3,224,224] -> A[b*196+hp*14+wp][c*256+p*16+q] bf16 ----
__global__ __launch_bounds__(256) void im2col_patches(
    const float* __restrict__ X, unsigned short* __restrict__ A) {
  int idx = blockIdx.x * 256 + threadIdx.x;
  if (idx >= NPATCH * Bn * Dn) return;
  int col = idx % Dn, row = idx / Dn;
  int b = row / NPATCH, pi = row % NPATCH;
  int hp = pi / 14, wp = pi % 14;
  int c = col >> 8, r2 = col & 255, p = r2 >> 4, q = r2 & 15;
  A[idx] = f2bf(X[(((size_t)b * 3 + c) * 224 + hp * 16 + p) * 224 + wp * 16 + q]);
}

// ---- x[b][0][:] = cls_token + pos_emb[0] ----
__global__ __launch_bounds__(256) void init_cls(
    const float* __restrict__ cls_tok, const float* __restrict__ pos_emb,
    float* __restrict__ x) {
  int i = blockIdx.x * 256 + threadIdx.x;
  if (i >= Bn * Dn) return;
  int b = i / Dn, d = i % Dn;
  x[(size_t)b * Sn * Dn + d] = cls_tok[d] + pos_emb[d];
}

// ---- pack per-layer qkv biases: bqkv[l][0:768]=bq, [768:1536]=bk, [1536:2304]=bv
__global__ __launch_bounds__(256) void pack_qkv_bias(
    const float* __restrict__ bq, const float* __restrict__ bk,
    const float* __restrict__ bv, float* __restrict__ out) {
  int i = blockIdx.x * 256 + threadIdx.x;
  if (i >= Ln * 3 * Dn) return;
  int l = i / (3 * Dn), r = i % (3 * Dn);
  int which = r / Dn, d = r % Dn;
  const float* src = which == 0 ? bq : (which == 1 ? bk : bv);
  out[i] = src[(size_t)l * Dn + d];
}

// ---- LayerNorm over D=768; out bf16 ----
__global__ __launch_bounds__(256) void layernorm_k(
    const float* __restrict__ x, int row_stride,
    const float* __restrict__ g, const float* __restrict__ b,
    unsigned short* __restrict__ out) {
  int row = blockIdx.x, t = threadIdx.x;
  const float* xr = x + (size_t)row * row_stride;
  float v0 = xr[t], v1 = xr[t + 256], v2 = xr[t + 512];
  float s = v0 + v1 + v2;
  __shared__ float red[4];
  int lane = t & 63, wid = t >> 6;
  for (int off = 32; off > 0; off >>= 1) s += __shfl_xor(s, off, 64);
  if (lane == 0) red[wid] = s;
  __syncthreads();
  float mean = (red[0] + red[1] + red[2] + red[3]) * (1.f / 768.f);
  __syncthreads();
  float d0 = v0 - mean, d1 = v1 - mean, d2 = v2 - mean;
  float q = d0 * d0 + d1 * d1 + d2 * d2;
  for (int off = 32; off > 0; off >>= 1) q += __shfl_xor(q, off, 64);
  if (lane == 0) red[wid] = q;
  __syncthreads();
  float var = (red[0] + red[1] + red[2] + red[3]) * (1.f / 768.f);
  float rstd = rsqrtf(var + 1e-5f);
  size_t o = (size_t)row * Dn;
  out[o + t]       = f2bf(d0 * rstd * g[t]       + b[t]);
  out[o + t + 256] = f2bf(d1 * rstd * g[t + 256] + b[t + 256]);
  out[o + t + 512] = f2bf(d2 * rstd * g[t + 512] + b[t + 512]);
}

// ---- m97-structure MFMA GEMM: 128x128 tile, 4 waves, 4x4 frags/wave,
//      global_load_lds width=16 staging, bijective XCD swizzle.
// C[M][N] = A[M][K](bf16, rows padded to mult of 128) * Bt[N][K](bf16)^T
// Requires: N % 128 == 0, K % 32 == 0. M handled by store guards + padded A.
// MODE 1: out fp32 [M][N] = acc+bias+res    (residual add, in-place on x ok)
// MODE 2: out bf16 [M][N] = gelu(acc+bias)
// MODE 3: patch: out fp32 x[b][1+pi][n] = acc+bias+pos_emb[(1+pi)*D+n]
// MODE 5: fused qkv: N=2304; Cb=qb base; qb/kb/vb contiguous, MPAD rows each
template <int MODE>
__global__ __launch_bounds__(256) void gemm128(
    const unsigned short* __restrict__ A, const unsigned short* __restrict__ Bt,
    const float* __restrict__ bias, const float* __restrict__ res,
    float* __restrict__ Cf, unsigned short* __restrict__ Cb,
    int M, int N, int K, int nbn) {
  __shared__ unsigned short As[128][32];
  __shared__ unsigned short Bs[128][32];
  // bijective XCD swizzle (m204): same-XCD blocks get consecutive tiles
  int nwg = gridDim.x;
  int orig = blockIdx.x;
  int qq = nwg >> 3, rr = nwg & 7;
  int xcd = orig & 7, loc = orig >> 3;
  int wg = (xcd < rr ? xcd * (qq + 1) : rr * (qq + 1) + (xcd - rr) * qq) + loc;
  int mb = wg / nbn, nb = wg % nbn;
  int m0 = mb * 128, n0 = nb * 128;

  int tid = threadIdx.x, wid = tid >> 6, lane = tid & 63;
  int wm = (wid >> 1) * 64, wn = (wid & 1) * 64;
  int lrow = lane & 15, lq = lane >> 4;
  // staging: lane covers As[wid*16 + lane/4][(lane&3)*8 ..+8] (= base+lane*16B)
  int sr = wid * 16 + (lane >> 2);
  int sc = (lane & 3) * 8;
  const unsigned short* Ap = A + (size_t)(m0 + sr) * K + sc;
  const unsigned short* Bp = Bt + (size_t)(n0 + sr) * K + sc;

  f32x4 acc[4][4] = {};
  for (int k0 = 0; k0 < K; k0 += 32) {
    gload16(Ap, &As[wid * 16][0]);
    gload16(Ap + (size_t)64 * K, &As[64 + wid * 16][0]);
    gload16(Bp, &Bs[wid * 16][0]);
    gload16(Bp + (size_t)64 * K, &Bs[64 + wid * 16][0]);
    Ap += 32; Bp += 32;
    __syncthreads();   // compiler drains vmcnt(0) -> tile ready
    short8 af[4], bfr[4];
#pragma unroll
    for (int tm = 0; tm < 4; tm++)
      af[tm] = *(const short8*)(&As[wm + tm * 16 + lrow][lq * 8]);
#pragma unroll
    for (int tn = 0; tn < 4; tn++)
      bfr[tn] = *(const short8*)(&Bs[wn + tn * 16 + lrow][lq * 8]);
#pragma unroll
    for (int tm = 0; tm < 4; tm++)
#pragma unroll
      for (int tn = 0; tn < 4; tn++)
        acc[tm][tn] = __builtin_amdgcn_mfma_f32_16x16x32_bf16(
            af[tm], bfr[tn], acc[tm][tn], 0, 0, 0);
    __syncthreads();   // all waves done reading before next overwrite
  }

  for (int tm = 0; tm < 4; tm++)
    for (int tn = 0; tn < 4; tn++)
      for (int r = 0; r < 4; r++) {
        int gm = m0 + wm + tm * 16 + lq * 4 + r;
        int gn = n0 + wn + tn * 16 + lrow;
        if (gm >= M || gn >= N) continue;
        float val = acc[tm][tn][r] + bias[gn];
        if constexpr (MODE == 1) {
          size_t o = (size_t)gm * N + gn;
          Cf[o] = val + res[o];
        } else if constexpr (MODE == 2) {
          float gl = 0.5f * val * (1.f + erff(val * 0.70710678118654752f));
          Cb[(size_t)gm * N + gn] = f2bf(gl);
        } else if constexpr (MODE == 3) {
          int b = gm / NPATCH, pi = gm % NPATCH;
          Cf[((size_t)b * Sn + 1 + pi) * Dn + gn] =
              val + res[(size_t)(1 + pi) * Dn + gn];
        } else if constexpr (MODE == 5) {
          int which = gn / Dn;            // 0=q 1=k 2=v
          int d = gn - which * Dn;
          int b = gm / Sn, s = gm % Sn;
          int h = d >> 6, dh = d & 63;
          Cb[(size_t)which * MPAD * Dn +
             (((size_t)b * Hn + h) * Sn + s) * DHn + dh] = f2bf(val);
        }
      }
}

// ---- small-M GEMM for the classifier head (N=1000 not mult of 128) ----
// MODE 4: out fp32 [M][N] = acc+bias
template <int MODE>
__global__ __launch_bounds__(256) void gemm64(
    const unsigned short* __restrict__ A, const unsigned short* __restrict__ Bt,
    const float* __restrict__ bias, const float* __restrict__ res,
    float* __restrict__ Cf, unsigned short* __restrict__ Cb,
    int M, int N, int K) {
  __shared__ unsigned short As[64][32];
  __shared__ unsigned short Bs[64][32];
  int m0 = blockIdx.x * 64, n0 = blockIdx.y * 64;
  int tid = threadIdx.x;
  int wid = tid >> 6, lane = tid & 63;
  int wm = (wid >> 1) * 32, wn = (wid & 1) * 32;
  int lrow = lane & 15, lq = lane >> 4;
  int lr = tid >> 2, lseg = (tid & 3) * 8;
  f32x4 acc[2][2] = {};
  for (int k0 = 0; k0 < K; k0 += 32) {
    int gm = m0 + lr;
    uint4 av = (gm < M) ? *(const uint4*)(A + (size_t)gm * K + k0 + lseg)
                        : make_uint4(0, 0, 0, 0);
    int gn = n0 + lr;
    uint4 bv = (gn < N) ? *(const uint4*)(Bt + (size_t)gn * K + k0 + lseg)
                        : make_uint4(0, 0, 0, 0);
    __syncthreads();
    *(uint4*)(&As[lr][lseg]) = av;
    *(uint4*)(&Bs[lr][lseg]) = bv;
    __syncthreads();
    short8 a0 = *(const short8*)(&As[wm + lrow][lq * 8]);
    short8 a1 = *(const short8*)(&As[wm + 16 + lrow][lq * 8]);
    short8 b0 = *(const short8*)(&Bs[wn + lrow][lq * 8]);
    short8 b1 = *(const short8*)(&Bs[wn + 16 + lrow][lq * 8]);
    acc[0][0] = __builtin_amdgcn_mfma_f32_16x16x32_bf16(a0, b0, acc[0][0], 0, 0, 0);
    acc[0][1] = __builtin_amdgcn_mfma_f32_16x16x32_bf16(a0, b1, acc[0][1], 0, 0, 0);
    acc[1][0] = __builtin_amdgcn_mfma_f32_16x16x32_bf16(a1, b0, acc[1][0], 0, 0, 0);
    acc[1][1] = __builtin_amdgcn_mfma_f32_16x16x32_bf16(a1, b1, acc[1][1], 0, 0, 0);
  }
  for (int tm = 0; tm < 2; tm++)
    for (int tn = 0; tn < 2; tn++)
      for (int r = 0; r < 4; r++) {
        int ml = wm + tm * 16 + lq * 4 + r;
        int nl = wn + tn * 16 + lrow;
        int gm = m0 + ml, gn = n0 + nl;
        if (gm >= M || gn >= N) continue;
        float val = acc[tm][tn][r] + bias[gn];
        if constexpr (MODE == 4) {
          Cf[(size_t)gm * N + gn] = val;
        }
      }
}

// ---- MFMA flash-style attention (unchanged) ----
#define QT 16
#define NKT 13        // ceil(197/16)
#define PJ 232        // padded j extent
__global__ __launch_bounds__(256) void attn_mfma(
    const unsigned short* __restrict__ q, const unsigned short* __restrict__ k,
    const unsigned short* __restrict__ v, unsigned short* __restrict__ out) {
  int bh = blockIdx.x, b = bh / Hn, h = bh % Hn;
  const unsigned short* qp = q + (size_t)bh * Sn * DHn;
  const unsigned short* kp = k + (size_t)bh * Sn * DHn;
  const unsigned short* vp = v + (size_t)bh * Sn * DHn;
  __shared__ unsigned short Vt[DHn][PJ];      // 64 x 232 bf16 = 29 KB
  __shared__ unsigned short Pl[4][QT][PJ];    // per-wave P,   = 29 KB
  int t = threadIdx.x, lane = t & 63, wid = t >> 6;
  int col = lane & 15, quad = lane >> 4;

  for (int i = t; i < Sn * DHn; i += 256) {
    int j = i >> 6, d = i & 63;
    Vt[d][j] = vp[i];
  }
  for (int i = t; i < DHn * (PJ - Sn); i += 256) {
    int d = i / (PJ - Sn), j = Sn + i % (PJ - Sn);
    Vt[d][j] = 0;
  }
  for (int i = lane; i < QT * (PJ - NKT * 16); i += 64) {
    int r = i / (PJ - NKT * 16), c = NKT * 16 + i % (PJ - NKT * 16);
    Pl[wid][r][c] = 0;
  }
  __syncthreads();

  for (int qt = wid; qt < NKT; qt += 4) {
    int q0 = qt * QT;
    int qrow = q0 + col;
    int qc = (qrow < Sn) ? qrow : (Sn - 1);
    short8 qa0 = *(const short8*)(qp + (size_t)qc * DHn + quad * 8);
    short8 qa1 = *(const short8*)(qp + (size_t)qc * DHn + 32 + quad * 8);

    f32x4 sc[NKT];
    for (int kt = 0; kt < NKT; kt++) {
      int krow = kt * QT + col;
      int kc = (krow < Sn) ? krow : (Sn - 1);
      short8 kb0 = *(const short8*)(kp + (size_t)kc * DHn + quad * 8);
      short8 kb1 = *(const short8*)(kp + (size_t)kc * DHn + 32 + quad * 8);
      f32x4 c = {};
      c = __builtin_amdgcn_mfma_f32_16x16x32_bf16(qa0, kb0, c, 0, 0, 0);
      c = __builtin_amdgcn_mfma_f32_16x16x32_bf16(qa1, kb1, c, 0, 0, 0);
      if (krow >= Sn)
        for (int r = 0; r < 4; r++) c[r] = -1e30f;
      sc[kt] = c;
    }

    for (int r = 0; r < 4; r++) {
      float m = -1e30f;
      for (int kt = 0; kt < NKT; kt++) m = fmaxf(m, sc[kt][r]);
      for (int off = 1; off < 16; off <<= 1) m = fmaxf(m, __shfl_xor(m, off, 64));
      float s = 0.f;
      for (int kt = 0; kt < NKT; kt++) {
        float e = __expf((sc[kt][r] - m) * 0.125f);
        sc[kt][r] = e;
        s += e;
      }
      for (int off = 1; off < 16; off <<= 1) s += __shfl_xor(s, off, 64);
      float inv = 1.f / s;
      int row = quad * 4 + r;
      for (int kt = 0; kt < NKT; kt++)
        Pl[wid][row][kt * 16 + col] = f2bf(sc[kt][r] * inv);
    }

    f32x4 o[4] = {};
    for (int jc = 0; jc < 7; jc++) {
      short8 pa = *(const short8*)(&Pl[wid][col][jc * 32 + quad * 8]);
      for (int dt = 0; dt < 4; dt++) {
        short8 vb = *(const short8*)(&Vt[dt * 16 + col][jc * 32 + quad * 8]);
        o[dt] = __builtin_amdgcn_mfma_f32_16x16x32_bf16(pa, vb, o[dt], 0, 0, 0);
      }
    }

    for (int dt = 0; dt < 4; dt++)
      for (int r = 0; r < 4; r++) {
        int qq = q0 + quad * 4 + r;
        if (qq < Sn)
          out[((size_t)b * Sn + qq) * Dn + h * DHn + dt * 16 + col] =
              f2bf(o[dt][r]);
      }
  }
}

extern "C" void kernel_launch(void* const* d_in, const int* in_sizes, int n_in,
                              void* d_out, int out_size, void* d_ws, size_t ws_size,
                              hipStream_t stream) {
  const float* X       = (const float*)d_in[0];
  const float* patch_w = (const float*)d_in[1];
  const float* patch_b = (const float*)d_in[2];
  const float* cls_tok = (const float*)d_in[3];
  const float* pos_emb = (const float*)d_in[4];
  const float* ln1_g = (const float*)d_in[5];
  const float* ln1_b = (const float*)d_in[6];
  const float* Wq = (const float*)d_in[7];
  const float* bq = (const float*)d_in[8];
  const float* Wk = (const float*)d_in[9];
  const float* bk = (const float*)d_in[10];
  const float* Wv = (const float*)d_in[11];
  const float* bv = (const float*)d_in[12];
  const float* Wo = (const float*)d_in[13];
  const float* bo = (const float*)d_in[14];
  const float* ln2_g = (const float*)d_in[15];
  const float* ln2_b = (const float*)d_in[16];
  const float* Wf1 = (const float*)d_in[17];
  const float* bf1 = (const float*)d_in[18];
  const float* Wf2 = (const float*)d_in[19];
  const float* bf2 = (const float*)d_in[20];
  const float* lnf_g = (const float*)d_in[21];
  const float* lnf_b = (const float*)d_in[22];
  const float* head_w = (const float*)d_in[23];
  const float* head_b = (const float*)d_in[24];
  float* out = (float*)d_out;

  char* base = (char*)d_ws;
  size_t off = 0;
  auto alloc = [&](size_t bytes) -> void* {
    void* p = base + off;
    off += (bytes + 255) & ~(size_t)255;
    return p;
  };
  // NOTE: wq_t/wk_t/wv_t must stay consecutive (fused QKV Bt = [2304][768]);
  // qb/kb/vb must stay consecutive with MPAD*Dn stride (fused QKV epilogue).
  unsigned short* wq_t  = (unsigned short*)alloc((size_t)Dn * Dn * 2);
  unsigned short* wk_t  = (unsigned short*)alloc((size_t)Dn * Dn * 2);
  unsigned short* wv_t  = (unsigned short*)alloc((size_t)Dn * Dn * 2);
  unsigned short* wo_t  = (unsigned short*)alloc((size_t)Dn * Dn * 2);
  unsigned short* wf1_t = (unsigned short*)alloc((size_t)Dn * Fn * 2);
  unsigned short* wf2_t = (unsigned short*)alloc((size_t)Dn * Fn * 2);
  unsigned short* pw_bf = (unsigned short*)alloc((size_t)Dn * Dn * 2);
  unsigned short* hw_t  = (unsigned short*)alloc((size_t)NCLSn * Dn * 2);
  unsigned short* im2c  = (unsigned short*)alloc((size_t)MPAD * Dn * 2);
  float*          x     = (float*)alloc((size_t)MTOK * Dn * 4);
  unsigned short* h_bf  = (unsigned short*)alloc((size_t)MPAD * Dn * 2);
  unsigned short* qb    = (unsigned short*)alloc((size_t)MPAD * Dn * 2);
  unsigned short* kb    = (unsigned short*)alloc((size_t)MPAD * Dn * 2);
  unsigned short* vb    = (unsigned short*)alloc((size_t)MPAD * Dn * 2);
  unsigned short* atob  = (unsigned short*)alloc((size_t)MPAD * Dn * 2);
  unsigned short* gel   = (unsigned short*)alloc((size_t)MPAD * Fn * 2);
  unsigned short* clsb  = (unsigned short*)alloc((size_t)Bn * Dn * 2);
  float*          bqkv  = (float*)alloc((size_t)Ln * 3 * Dn * 4);
  (void)ws_size; (void)in_sizes; (void)n_in; (void)out_size;

  dim3 tb(32, 8);
  auto tgrid = [](int rows, int cols) { return dim3((cols + 31) / 32, (rows + 31) / 32); };
  auto g128 = [](int M, int N) {
    return dim3((unsigned)(((M + 127) / 128) * ((N + 127) / 128)));
  };

  // prologue
  cast_bf<<<(Dn * Dn + 255) / 256, 256, 0, stream>>>(patch_w, pw_bf, Dn * Dn);
  transpose_cast<<<tgrid(Dn, NCLSn), tb, 0, stream>>>(head_w, hw_t, Dn, NCLSn);
  pack_qkv_bias<<<(Ln * 3 * Dn + 255) / 256, 256, 0, stream>>>(bq, bk, bv, bqkv);
  im2col_patches<<<(Bn * NPATCH * Dn + 255) / 256, 256, 0, stream>>>(X, im2c);
  init_cls<<<(Bn * Dn + 255) / 256, 256, 0, stream>>>(cls_tok, pos_emb, x);
  gemm128<3><<<g128(Bn * NPATCH, Dn), 256, 0, stream>>>(
      im2c, pw_bf, patch_b, pos_emb, x, nullptr, Bn * NPATCH, Dn, Dn, Dn / 128);

  for (int l = 0; l < Ln; l++) {
    const size_t wo_off = (size_t)l * Dn * Dn;
    const size_t wf_off = (size_t)l * Dn * Fn;
    transpose_cast<<<tgrid(Dn, Dn), tb, 0, stream>>>(Wq + wo_off, wq_t, Dn, Dn);
    transpose_cast<<<tgrid(Dn, Dn), tb, 0, stream>>>(Wk + wo_off, wk_t, Dn, Dn);
    transpose_cast<<<tgrid(Dn, Dn), tb, 0, stream>>>(Wv + wo_off, wv_t, Dn, Dn);
    transpose_cast<<<tgrid(Dn, Dn), tb, 0, stream>>>(Wo + wo_off, wo_t, Dn, Dn);
    transpose_cast<<<tgrid(Dn, Fn), tb, 0, stream>>>(Wf1 + wf_off, wf1_t, Dn, Fn);
    transpose_cast<<<tgrid(Fn, Dn), tb, 0, stream>>>(Wf2 + wf_off, wf2_t, Fn, Dn);

    layernorm_k<<<MTOK, 256, 0, stream>>>(x, Dn, ln1_g + (size_t)l * Dn,
                                          ln1_b + (size_t)l * Dn, h_bf);
    // fused QKV: Bt = [wq_t|wk_t|wv_t] contiguous = [2304][768]
    gemm128<5><<<g128(MTOK, 3 * Dn), 256, 0, stream>>>(
        h_bf, wq_t, bqkv + (size_t)l * 3 * Dn, nullptr, nullptr, qb,
        MTOK, 3 * Dn, Dn, 3 * Dn / 128);
    attn_mfma<<<Bn * Hn, 256, 0, stream>>>(qb, kb, vb, atob);
    gemm128<1><<<g128(MTOK, Dn), 256, 0, stream>>>(
        atob, wo_t, bo + (size_t)l * Dn, x, x, nullptr, MTOK, Dn, Dn, Dn / 128);
    layernorm_k<<<MTOK, 256, 0, stream>>>(x, Dn, ln2_g + (size_t)l * Dn,
                                          ln2_b + (size_t)l * Dn, h_bf);
    gemm128<2><<<g128(MTOK, Fn), 256, 0, stream>>>(
        h_bf, wf1_t, bf1 + (size_t)l * Fn, nullptr, nullptr, gel,
        MTOK, Fn, Dn, Fn / 128);
    gemm128<1><<<g128(MTOK, Dn), 256, 0, stream>>>(
        gel, wf2_t, bf2 + (size_t)l * Dn, x, x, nullptr, MTOK, Dn, Fn, Dn / 128);
  }

  layernorm_k<<<Bn, 256, 0, stream>>>(x, Sn * Dn, lnf_g, lnf_b, clsb);
  gemm64<4><<<dim3(1, (NCLSn + 63) / 64), 256, 0, stream>>>(
      clsb, hw_t, head_b, nullptr, out, nullptr, Bn, NCLSn, Dn);
}

// Round 3
// 4358.826 us; speedup vs baseline: 3.8325x; 3.8325x over previous
//
#include <hip/hip_runtime.h>
#include <math.h>

// ---- problem constants ----
#define Bn 32
#define Sn 197
#define Dn 768
#define Hn 12
#define DHn 64
#define Fn 3072
#define Ln 12
#define NPATCH 196
#define NCLSn 1000
#define MTOK (Bn * Sn)   // 6304
#define MPAD 6400        // MTOK padded to multiple of 128 (gemm128 staging reads)

typedef __attribute__((ext_vector_type(8))) short short8;
typedef __attribute__((ext_vector_type(4))) float f32x4;

__device__ __forceinline__ unsigned short f2bf(float f) {
  union { float f; unsigned int u; } v; v.f = f;
  unsigned int r = v.u + 0x7fffu + ((v.u >> 16) & 1u);
  return (unsigned short)(r >> 16);
}
__device__ __forceinline__ float bf2f(unsigned short h) {
  union { unsigned int u; float f; } v; v.u = ((unsigned int)h) << 16;
  return v.f;
}

// direct HBM -> LDS DMA, 16B per lane (dest = wave-uniform base + lane*16)
__device__ __forceinline__ void gload16(const unsigned short* g, unsigned short* l) {
  __builtin_amdgcn_global_load_lds(
      (const __attribute__((address_space(1))) unsigned int*)g,
      (__attribute__((address_space(3))) unsigned int*)l, 16, 0, 0);
}

// ---- transpose + cast fp32[rows][cols] -> bf16[cols][rows] ----
__global__ __launch_bounds__(256) void transpose_cast(
    const float* __restrict__ in, unsigned short* __restrict__ out,
    int rows, int cols) {
  __shared__ float tile[32][33];
  int c0 = blockIdx.x * 32, r0 = blockIdx.y * 32;
  int tx = threadIdx.x, ty = threadIdx.y;
  for (int i = 0; i < 32; i += 8) {
    int r = r0 + ty + i, c = c0 + tx;
    tile[ty + i][tx] = (r < rows && c < cols) ? in[(size_t)r * cols + c] : 0.f;
  }
  __syncthreads();
  for (int i = 0; i < 32; i += 8) {
    int c = c0 + ty + i, r = r0 + tx;
    if (c < cols && r < rows)
      out[(size_t)c * rows + r] = f2bf(tile[tx][ty + i]);
  }
}

// ---- plain cast fp32 -> bf16 ----
__global__ __launch_bounds__(256) void cast_bf(
    const float* __restrict__ in, unsigned short* __restrict__ out, int n) {
  int i = blockIdx.x * 256 + threadIdx.x;
  if (i < n) out[i] = f2bf(in[i]);
}

// ---- im2col: X[B,3,224,224] -> A[b*196+hp*14+wp][c*256+p*16+q] bf16 ----
__global__ __launch_bounds__(256) void im2col_patches(
    const float* __restrict__ X, unsigned short* __restrict__ A) {
  int idx = blockIdx.x * 256 + threadIdx.x;
  if (idx >= NPATCH * Bn * Dn) return;
  int col = idx % Dn, row = idx / Dn;
  int b = row / NPATCH, pi = row % NPATCH;
  int hp = pi / 14, wp = pi % 14;
  int c = col >> 8, r2 = col & 255, p = r2 >> 4, q = r2 & 15;
  A[idx] = f2bf(X[(((size_t)b * 3 + c) * 224 + hp * 16 + p) * 224 + wp * 16 + q]);
}

// ---- x[b][0][:] = cls_token + pos_emb[0] ----
__global__ __launch_bounds__(256) void init_cls(
    const float* __restrict__ cls_tok, const float* __restrict__ pos_emb,
    float* __restrict__ x) {
  int i = blockIdx.x * 256 + threadIdx.x;
  if (i >= Bn * Dn) return;
  int b = i / Dn, d = i % Dn;
  x[(size_t)b * Sn * Dn + d] = cls_tok[d] + pos_emb[d];
}

// ---- pack per-layer qkv biases: bqkv[l][0:768]=bq, [768:1536]=bk, [1536:2304]=bv
__global__ __launch_bounds__(256) void pack_qkv_bias(
    const float* __restrict__ bq, const float* __restrict__ bk,
    const float* __restrict__ bv, float* __restrict__ out) {
  int i = blockIdx.x * 256 + threadIdx.x;
  if (i >= Ln * 3 * Dn) return;
  int l = i / (3 * Dn), r = i % (3 * Dn);
  int which = r / Dn, d = r % Dn;
  const float* src = which == 0 ? bq : (which == 1 ? bk : bv);
  out[i] = src[(size_t)l * Dn + d];
}

// ---- LayerNorm over D=768; out bf16 ----
__global__ __launch_bounds__(256) void layernorm_k(
    const float* __restrict__ x, int row_stride,
    const float* __restrict__ g, const float* __restrict__ b,
    unsigned short* __restrict__ out) {
  int row = blockIdx.x, t = threadIdx.x;
  const float* xr = x + (size_t)row * row_stride;
  float v0 = xr[t], v1 = xr[t + 256], v2 = xr[t + 512];
  float s = v0 + v1 + v2;
  __shared__ float red[4];
  int lane = t & 63, wid = t >> 6;
  for (int off = 32; off > 0; off >>= 1) s += __shfl_xor(s, off, 64);
  if (lane == 0) red[wid] = s;
  __syncthreads();
  float mean = (red[0] + red[1] + red[2] + red[3]) * (1.f / 768.f);
  __syncthreads();
  float d0 = v0 - mean, d1 = v1 - mean, d2 = v2 - mean;
  float q = d0 * d0 + d1 * d1 + d2 * d2;
  for (int off = 32; off > 0; off >>= 1) q += __shfl_xor(q, off, 64);
  if (lane == 0) red[wid] = q;
  __syncthreads();
  float var = (red[0] + red[1] + red[2] + red[3]) * (1.f / 768.f);
  float rstd = rsqrtf(var + 1e-5f);
  size_t o = (size_t)row * Dn;
  out[o + t]       = f2bf(d0 * rstd * g[t]       + b[t]);
  out[o + t + 256] = f2bf(d1 * rstd * g[t + 256] + b[t + 256]);
  out[o + t + 512] = f2bf(d2 * rstd * g[t + 512] + b[t + 512]);
}

// ---- m97-structure MFMA GEMM: 128x128 tile, 4 waves, 4x4 frags/wave,
//      global_load_lds width=16 staging, bijective XCD swizzle.
// C[M][N] = A[M][K](bf16, rows padded to mult of 128) * Bt[N][K](bf16)^T
// Requires: N % 128 == 0, K % 32 == 0. M handled by store guards + padded A.
// NOTE: epilogue loops MUST be fully unrolled — runtime indexing of acc[][]
// demotes the whole accumulator array to scratch (rule #20), which turns the
// K-loop into a scratch-bandwidth kernel (measured: WRITE_SIZE 1.9 GB, 1.8%
// MfmaUtil, VGPR_Count 28 in round 2).
// MODE 1: out fp32 [M][N] = acc+bias+res    (residual add, in-place on x ok)
// MODE 2: out bf16 [M][N] = gelu(acc+bias)
// MODE 3: patch: out fp32 x[b][1+pi][n] = acc+bias+pos_emb[(1+pi)*D+n]
// MODE 5: fused qkv: N=2304; Cb=qb base; qb/kb/vb contiguous, MPAD rows each
template <int MODE>
__global__ __launch_bounds__(256) void gemm128(
    const unsigned short* __restrict__ A, const unsigned short* __restrict__ Bt,
    const float* __restrict__ bias, const float* __restrict__ res,
    float* __restrict__ Cf, unsigned short* __restrict__ Cb,
    int M, int N, int K, int nbn) {
  __shared__ unsigned short As[128][32];
  __shared__ unsigned short Bs[128][32];
  // bijective XCD swizzle (m204): same-XCD blocks get consecutive tiles
  int nwg = gridDim.x;
  int orig = blockIdx.x;
  int qq = nwg >> 3, rr = nwg & 7;
  int xcd = orig & 7, loc = orig >> 3;
  int wg = (xcd < rr ? xcd * (qq + 1) : rr * (qq + 1) + (xcd - rr) * qq) + loc;
  int mb = wg / nbn, nb = wg % nbn;
  int m0 = mb * 128, n0 = nb * 128;

  int tid = threadIdx.x, wid = tid >> 6, lane = tid & 63;
  int wm = (wid >> 1) * 64, wn = (wid & 1) * 64;
  int lrow = lane & 15, lq = lane >> 4;
  // staging: lane covers As[wid*16 + lane/4][(lane&3)*8 ..+8] (= base+lane*16B)
  int sr = wid * 16 + (lane >> 2);
  int sc = (lane & 3) * 8;
  const unsigned short* Ap = A + (size_t)(m0 + sr) * K + sc;
  const unsigned short* Bp = Bt + (size_t)(n0 + sr) * K + sc;

  f32x4 acc[4][4] = {};
  for (int k0 = 0; k0 < K; k0 += 32) {
    gload16(Ap, &As[wid * 16][0]);
    gload16(Ap + (size_t)64 * K, &As[64 + wid * 16][0]);
    gload16(Bp, &Bs[wid * 16][0]);
    gload16(Bp + (size_t)64 * K, &Bs[64 + wid * 16][0]);
    Ap += 32; Bp += 32;
    __syncthreads();   // compiler drains vmcnt(0) -> tile ready
    short8 af[4], bfr[4];
#pragma unroll
    for (int tm = 0; tm < 4; tm++)
      af[tm] = *(const short8*)(&As[wm + tm * 16 + lrow][lq * 8]);
#pragma unroll
    for (int tn = 0; tn < 4; tn++)
      bfr[tn] = *(const short8*)(&Bs[wn + tn * 16 + lrow][lq * 8]);
#pragma unroll
    for (int tm = 0; tm < 4; tm++)
#pragma unroll
      for (int tn = 0; tn < 4; tn++)
        acc[tm][tn] = __builtin_amdgcn_mfma_f32_16x16x32_bf16(
            af[tm], bfr[tn], acc[tm][tn], 0, 0, 0);
    __syncthreads();   // all waves done reading before next overwrite
  }

#pragma unroll
  for (int tm = 0; tm < 4; tm++)
#pragma unroll
    for (int tn = 0; tn < 4; tn++)
#pragma unroll
      for (int r = 0; r < 4; r++) {
        int gm = m0 + wm + tm * 16 + lq * 4 + r;
        int gn = n0 + wn + tn * 16 + lrow;
        if (gm >= M || gn >= N) continue;
        float val = acc[tm][tn][r] + bias[gn];
        if constexpr (MODE == 1) {
          size_t o = (size_t)gm * N + gn;
          Cf[o] = val + res[o];
        } else if constexpr (MODE == 2) {
          float gl = 0.5f * val * (1.f + erff(val * 0.70710678118654752f));
          Cb[(size_t)gm * N + gn] = f2bf(gl);
        } else if constexpr (MODE == 3) {
          int b = gm / NPATCH, pi = gm % NPATCH;
          Cf[((size_t)b * Sn + 1 + pi) * Dn + gn] =
              val + res[(size_t)(1 + pi) * Dn + gn];
        } else if constexpr (MODE == 5) {
          int which = gn / Dn;            // 0=q 1=k 2=v
          int d = gn - which * Dn;
          int b = gm / Sn, s = gm % Sn;
          int h = d >> 6, dh = d & 63;
          Cb[(size_t)which * MPAD * Dn +
             (((size_t)b * Hn + h) * Sn + s) * DHn + dh] = f2bf(val);
        }
      }
}

// ---- small-M GEMM for the classifier head (N=1000 not mult of 128) ----
// MODE 4: out fp32 [M][N] = acc+bias
template <int MODE>
__global__ __launch_bounds__(256) void gemm64(
    const unsigned short* __restrict__ A, const unsigned short* __restrict__ Bt,
    const float* __restrict__ bias, const float* __restrict__ res,
    float* __restrict__ Cf, unsigned short* __restrict__ Cb,
    int M, int N, int K) {
  __shared__ unsigned short As[64][32];
  __shared__ unsigned short Bs[64][32];
  int m0 = blockIdx.x * 64, n0 = blockIdx.y * 64;
  int tid = threadIdx.x;
  int wid = tid >> 6, lane = tid & 63;
  int wm = (wid >> 1) * 32, wn = (wid & 1) * 32;
  int lrow = lane & 15, lq = lane >> 4;
  int lr = tid >> 2, lseg = (tid & 3) * 8;
  f32x4 acc[2][2] = {};
  for (int k0 = 0; k0 < K; k0 += 32) {
    int gm = m0 + lr;
    uint4 av = (gm < M) ? *(const uint4*)(A + (size_t)gm * K + k0 + lseg)
                        : make_uint4(0, 0, 0, 0);
    int gn = n0 + lr;
    uint4 bv = (gn < N) ? *(const uint4*)(Bt + (size_t)gn * K + k0 + lseg)
                        : make_uint4(0, 0, 0, 0);
    __syncthreads();
    *(uint4*)(&As[lr][lseg]) = av;
    *(uint4*)(&Bs[lr][lseg]) = bv;
    __syncthreads();
    short8 a0 = *(const short8*)(&As[wm + lrow][lq * 8]);
    short8 a1 = *(const short8*)(&As[wm + 16 + lrow][lq * 8]);
    short8 b0 = *(const short8*)(&Bs[wn + lrow][lq * 8]);
    short8 b1 = *(const short8*)(&Bs[wn + 16 + lrow][lq * 8]);
    acc[0][0] = __builtin_amdgcn_mfma_f32_16x16x32_bf16(a0, b0, acc[0][0], 0, 0, 0);
    acc[0][1] = __builtin_amdgcn_mfma_f32_16x16x32_bf16(a0, b1, acc[0][1], 0, 0, 0);
    acc[1][0] = __builtin_amdgcn_mfma_f32_16x16x32_bf16(a1, b0, acc[1][0], 0, 0, 0);
    acc[1][1] = __builtin_amdgcn_mfma_f32_16x16x32_bf16(a1, b1, acc[1][1], 0, 0, 0);
  }
#pragma unroll
  for (int tm = 0; tm < 2; tm++)
#pragma unroll
    for (int tn = 0; tn < 2; tn++)
#pragma unroll
      for (int r = 0; r < 4; r++) {
        int ml = wm + tm * 16 + lq * 4 + r;
        int nl = wn + tn * 16 + lrow;
        int gm = m0 + ml, gn = n0 + nl;
        if (gm >= M || gn >= N) continue;
        float val = acc[tm][tn][r] + bias[gn];
        if constexpr (MODE == 4) {
          Cf[(size_t)gm * N + gn] = val;
        }
      }
}

// ---- MFMA flash-style attention (unchanged) ----
#define QT 16
#define NKT 13        // ceil(197/16)
#define PJ 232        // padded j extent
__global__ __launch_bounds__(256) void attn_mfma(
    const unsigned short* __restrict__ q, const unsigned short* __restrict__ k,
    const unsigned short* __restrict__ v, unsigned short* __restrict__ out) {
  int bh = blockIdx.x, b = bh / Hn, h = bh % Hn;
  const unsigned short* qp = q + (size_t)bh * Sn * DHn;
  const unsigned short* kp = k + (size_t)bh * Sn * DHn;
  const unsigned short* vp = v + (size_t)bh * Sn * DHn;
  __shared__ unsigned short Vt[DHn][PJ];      // 64 x 232 bf16 = 29 KB
  __shared__ unsigned short Pl[4][QT][PJ];    // per-wave P,   = 29 KB
  int t = threadIdx.x, lane = t & 63, wid = t >> 6;
  int col = lane & 15, quad = lane >> 4;

  for (int i = t; i < Sn * DHn; i += 256) {
    int j = i >> 6, d = i & 63;
    Vt[d][j] = vp[i];
  }
  for (int i = t; i < DHn * (PJ - Sn); i += 256) {
    int d = i / (PJ - Sn), j = Sn + i % (PJ - Sn);
    Vt[d][j] = 0;
  }
  for (int i = lane; i < QT * (PJ - NKT * 16); i += 64) {
    int r = i / (PJ - NKT * 16), c = NKT * 16 + i % (PJ - NKT * 16);
    Pl[wid][r][c] = 0;
  }
  __syncthreads();

  for (int qt = wid; qt < NKT; qt += 4) {
    int q0 = qt * QT;
    int qrow = q0 + col;
    int qc = (qrow < Sn) ? qrow : (Sn - 1);
    short8 qa0 = *(const short8*)(qp + (size_t)qc * DHn + quad * 8);
    short8 qa1 = *(const short8*)(qp + (size_t)qc * DHn + 32 + quad * 8);

    f32x4 sc[NKT];
    for (int kt = 0; kt < NKT; kt++) {
      int krow = kt * QT + col;
      int kc = (krow < Sn) ? krow : (Sn - 1);
      short8 kb0 = *(const short8*)(kp + (size_t)kc * DHn + quad * 8);
      short8 kb1 = *(const short8*)(kp + (size_t)kc * DHn + 32 + quad * 8);
      f32x4 c = {};
      c = __builtin_amdgcn_mfma_f32_16x16x32_bf16(qa0, kb0, c, 0, 0, 0);
      c = __builtin_amdgcn_mfma_f32_16x16x32_bf16(qa1, kb1, c, 0, 0, 0);
      if (krow >= Sn)
        for (int r = 0; r < 4; r++) c[r] = -1e30f;
      sc[kt] = c;
    }

    for (int r = 0; r < 4; r++) {
      float m = -1e30f;
      for (int kt = 0; kt < NKT; kt++) m = fmaxf(m, sc[kt][r]);
      for (int off = 1; off < 16; off <<= 1) m = fmaxf(m, __shfl_xor(m, off, 64));
      float s = 0.f;
      for (int kt = 0; kt < NKT; kt++) {
        float e = __expf((sc[kt][r] - m) * 0.125f);
        sc[kt][r] = e;
        s += e;
      }
      for (int off = 1; off < 16; off <<= 1) s += __shfl_xor(s, off, 64);
      float inv = 1.f / s;
      int row = quad * 4 + r;
      for (int kt = 0; kt < NKT; kt++)
        Pl[wid][row][kt * 16 + col] = f2bf(sc[kt][r] * inv);
    }

    f32x4 o[4] = {};
    for (int jc = 0; jc < 7; jc++) {
      short8 pa = *(const short8*)(&Pl[wid][col][jc * 32 + quad * 8]);
      for (int dt = 0; dt < 4; dt++) {
        short8 vb = *(const short8*)(&Vt[dt * 16 + col][jc * 32 + quad * 8]);
        o[dt] = __builtin_amdgcn_mfma_f32_16x16x32_bf16(pa, vb, o[dt], 0, 0, 0);
      }
    }

    for (int dt = 0; dt < 4; dt++)
      for (int r = 0; r < 4; r++) {
        int qq = q0 + quad * 4 + r;
        if (qq < Sn)
          out[((size_t)b * Sn + qq) * Dn + h * DHn + dt * 16 + col] =
              f2bf(o[dt][r]);
      }
  }
}

extern "C" void kernel_launch(void* const* d_in, const int* in_sizes, int n_in,
                              void* d_out, int out_size, void* d_ws, size_t ws_size,
                              hipStream_t stream) {
  const float* X       = (const float*)d_in[0];
  const float* patch_w = (const float*)d_in[1];
  const float* patch_b = (const float*)d_in[2];
  const float* cls_tok = (const float*)d_in[3];
  const float* pos_emb = (const float*)d_in[4];
  const float* ln1_g = (const float*)d_in[5];
  const float* ln1_b = (const float*)d_in[6];
  const float* Wq = (const float*)d_in[7];
  const float* bq = (const float*)d_in[8];
  const float* Wk = (const float*)d_in[9];
  const float* bk = (const float*)d_in[10];
  const float* Wv = (const float*)d_in[11];
  const float* bv = (const float*)d_in[12];
  const float* Wo = (const float*)d_in[13];
  const float* bo = (const float*)d_in[14];
  const float* ln2_g = (const float*)d_in[15];
  const float* ln2_b = (const float*)d_in[16];
  const float* Wf1 = (const float*)d_in[17];
  const float* bf1 = (const float*)d_in[18];
  const float* Wf2 = (const float*)d_in[19];
  const float* bf2 = (const float*)d_in[20];
  const float* lnf_g = (const float*)d_in[21];
  const float* lnf_b = (const float*)d_in[22];
  const float* head_w = (const float*)d_in[23];
  const float* head_b = (const float*)d_in[24];
  float* out = (float*)d_out;

  char* base = (char*)d_ws;
  size_t off = 0;
  auto alloc = [&](size_t bytes) -> void* {
    void* p = base + off;
    off += (bytes + 255) & ~(size_t)255;
    return p;
  };
  // NOTE: wq_t/wk_t/wv_t must stay consecutive (fused QKV Bt = [2304][768]);
  // qb/kb/vb must stay consecutive with MPAD*Dn stride (fused QKV epilogue).
  unsigned short* wq_t  = (unsigned short*)alloc((size_t)Dn * Dn * 2);
  unsigned short* wk_t  = (unsigned short*)alloc((size_t)Dn * Dn * 2);
  unsigned short* wv_t  = (unsigned short*)alloc((size_t)Dn * Dn * 2);
  unsigned short* wo_t  = (unsigned short*)alloc((size_t)Dn * Dn * 2);
  unsigned short* wf1_t = (unsigned short*)alloc((size_t)Dn * Fn * 2);
  unsigned short* wf2_t = (unsigned short*)alloc((size_t)Dn * Fn * 2);
  unsigned short* pw_bf = (unsigned short*)alloc((size_t)Dn * Dn * 2);
  unsigned short* hw_t  = (unsigned short*)alloc((size_t)NCLSn * Dn * 2);
  unsigned short* im2c  = (unsigned short*)alloc((size_t)MPAD * Dn * 2);
  float*          x     = (float*)alloc((size_t)MTOK * Dn * 4);
  unsigned short* h_bf  = (unsigned short*)alloc((size_t)MPAD * Dn * 2);
  unsigned short* qb    = (unsigned short*)alloc((size_t)MPAD * Dn * 2);
  unsigned short* kb    = (unsigned short*)alloc((size_t)MPAD * Dn * 2);
  unsigned short* vb    = (unsigned short*)alloc((size_t)MPAD * Dn * 2);
  unsigned short* atob  = (unsigned short*)alloc((size_t)MPAD * Dn * 2);
  unsigned short* gel   = (unsigned short*)alloc((size_t)MPAD * Fn * 2);
  unsigned short* clsb  = (unsigned short*)alloc((size_t)Bn * Dn * 2);
  float*          bqkv  = (float*)alloc((size_t)Ln * 3 * Dn * 4);
  (void)ws_size; (void)in_sizes; (void)n_in; (void)out_size;

  dim3 tb(32, 8);
  auto tgrid = [](int rows, int cols) { return dim3((cols + 31) / 32, (rows + 31) / 32); };
  auto g128 = [](int M, int N) {
    return dim3((unsigned)(((M + 127) / 128) * ((N + 127) / 128)));
  };

  // prologue
  cast_bf<<<(Dn * Dn + 255) / 256, 256, 0, stream>>>(patch_w, pw_bf, Dn * Dn);
  transpose_cast<<<tgrid(Dn, NCLSn), tb, 0, stream>>>(head_w, hw_t, Dn, NCLSn);
  pack_qkv_bias<<<(Ln * 3 * Dn + 255) / 256, 256, 0, stream>>>(bq, bk, bv, bqkv);
  im2col_patches<<<(Bn * NPATCH * Dn + 255) / 256, 256, 0, stream>>>(X, im2c);
  init_cls<<<(Bn * Dn + 255) / 256, 256, 0, stream>>>(cls_tok, pos_emb, x);
  gemm128<3><<<g128(Bn * NPATCH, Dn), 256, 0, stream>>>(
      im2c, pw_bf, patch_b, pos_emb, x, nullptr, Bn * NPATCH, Dn, Dn, Dn / 128);

  for (int l = 0; l < Ln; l++) {
    const size_t wo_off = (size_t)l * Dn * Dn;
    const size_t wf_off = (size_t)l * Dn * Fn;
    transpose_cast<<<tgrid(Dn, Dn), tb, 0, stream>>>(Wq + wo_off, wq_t, Dn, Dn);
    transpose_cast<<<tgrid(Dn, Dn), tb, 0, stream>>>(Wk + wo_off, wk_t, Dn, Dn);
    transpose_cast<<<tgrid(Dn, Dn), tb, 0, stream>>>(Wv + wo_off, wv_t, Dn, Dn);
    transpose_cast<<<tgrid(Dn, Dn), tb, 0, stream>>>(Wo + wo_off, wo_t, Dn, Dn);
    transpose_cast<<<tgrid(Dn, Fn), tb, 0, stream>>>(Wf1 + wf_off, wf1_t, Dn, Fn);
    transpose_cast<<<tgrid(Fn, Dn), tb, 0, stream>>>(Wf2 + wf_off, wf2_t, Fn, Dn);

    layernorm_k<<<MTOK, 256, 0, stream>>>(x, Dn, ln1_g + (size_t)l * Dn,
                                          ln1_b + (size_t)l * Dn, h_bf);
    // fused QKV: Bt = [wq_t|wk_t|wv_t] contiguous = [2304][768]
    gemm128<5><<<g128(MTOK, 3 * Dn), 256, 0, stream>>>(
        h_bf, wq_t, bqkv + (size_t)l * 3 * Dn, nullptr, nullptr, qb,
        MTOK, 3 * Dn, Dn, 3 * Dn / 128);
    attn_mfma<<<Bn * Hn, 256, 0, stream>>>(qb, kb, vb, atob);
    gemm128<1><<<g128(MTOK, Dn), 256, 0, stream>>>(
        atob, wo_t, bo + (size_t)l * Dn, x, x, nullptr, MTOK, Dn, Dn, Dn / 128);
    layernorm_k<<<MTOK, 256, 0, stream>>>(x, Dn, ln2_g + (size_t)l * Dn,
                                          ln2_b + (size_t)l * Dn, h_bf);
    gemm128<2><<<g128(MTOK, Fn), 256, 0, stream>>>(
        h_bf, wf1_t, bf1 + (size_t)l * Fn, nullptr, nullptr, gel,
        MTOK, Fn, Dn, Fn / 128);
    gemm128<1><<<g128(MTOK, Dn), 256, 0, stream>>>(
        gel, wf2_t, bf2 + (size_t)l * Dn, x, x, nullptr, MTOK, Dn, Fn, Dn / 128);
  }

  layernorm_k<<<Bn, 256, 0, stream>>>(x, Sn * Dn, lnf_g, lnf_b, clsb);
  gemm64<4><<<dim3(1, (NCLSn + 63) / 64), 256, 0, stream>>>(
      clsb, hw_t, head_b, nullptr, out, nullptr, Bn, NCLSn, Dn);
}

// Round 5
// 3935.345 us; speedup vs baseline: 4.2450x; 1.1076x over previous
//
#include <hip/hip_runtime.h>
#include <math.h>

// ---- problem constants ----
#define Bn 32
#define Sn 197
#define Dn 768
#define Hn 12
#define DHn 64
#define Fn 3072
#define Ln 12
#define NPATCH 196
#define NCLSn 1000
#define MTOK (Bn * Sn)   // 6304
#define MPAD 6400        // MTOK padded to multiple of 128 (gemm128 staging reads)

typedef __attribute__((ext_vector_type(8))) short short8;
typedef __attribute__((ext_vector_type(4))) float f32x4;

__device__ __forceinline__ unsigned short f2bf(float f) {
  union { float f; unsigned int u; } v; v.f = f;
  unsigned int r = v.u + 0x7fffu + ((v.u >> 16) & 1u);
  return (unsigned short)(r >> 16);
}
__device__ __forceinline__ float bf2f(unsigned short h) {
  union { unsigned int u; float f; } v; v.u = ((unsigned int)h) << 16;
  return v.f;
}

// direct HBM -> LDS DMA, 16B per lane (dest = wave-uniform base + lane*16)
__device__ __forceinline__ void gload16(const unsigned short* g, unsigned short* l) {
  __builtin_amdgcn_global_load_lds(
      (const __attribute__((address_space(1))) unsigned int*)g,
      (__attribute__((address_space(3))) unsigned int*)l, 16, 0, 0);
}

// ---- transpose + cast fp32[rows][cols] -> bf16[cols][rows] ----
__global__ __launch_bounds__(256) void transpose_cast(
    const float* __restrict__ in, unsigned short* __restrict__ out,
    int rows, int cols) {
  __shared__ float tile[32][33];
  int c0 = blockIdx.x * 32, r0 = blockIdx.y * 32;
  int tx = threadIdx.x, ty = threadIdx.y;
  for (int i = 0; i < 32; i += 8) {
    int r = r0 + ty + i, c = c0 + tx;
    tile[ty + i][tx] = (r < rows && c < cols) ? in[(size_t)r * cols + c] : 0.f;
  }
  __syncthreads();
  for (int i = 0; i < 32; i += 8) {
    int c = c0 + ty + i, r = r0 + tx;
    if (c < cols && r < rows)
      out[(size_t)c * rows + r] = f2bf(tile[tx][ty + i]);
  }
}

// ---- batched (z = layer) transpose+cast; writes out[(c+coff)*rows + r] ----
__global__ __launch_bounds__(256) void transpose_cast_b(
    const float* __restrict__ in, unsigned short* __restrict__ out,
    int rows, int cols, size_t in_ls, size_t out_ls, int coff) {
  __shared__ float tile[32][33];
  int l = blockIdx.z;
  in += (size_t)l * in_ls;
  out += (size_t)l * out_ls;
  int c0 = blockIdx.x * 32, r0 = blockIdx.y * 32;
  int tx = threadIdx.x, ty = threadIdx.y;
  for (int i = 0; i < 32; i += 8) {
    int r = r0 + ty + i, c = c0 + tx;
    tile[ty + i][tx] = (r < rows && c < cols) ? in[(size_t)r * cols + c] : 0.f;
  }
  __syncthreads();
  for (int i = 0; i < 32; i += 8) {
    int c = c0 + ty + i, r = r0 + tx;
    if (c < cols && r < rows)
      out[(size_t)(c + coff) * rows + r] = f2bf(tile[tx][ty + i]);
  }
}

// ---- plain cast fp32 -> bf16 ----
__global__ __launch_bounds__(256) void cast_bf(
    const float* __restrict__ in, unsigned short* __restrict__ out, int n) {
  int i = blockIdx.x * 256 + threadIdx.x;
  if (i < n) out[i] = f2bf(in[i]);
}

// ---- im2col: X[B,3,224,224] -> A[b*196+hp*14+wp][c*256+p*16+q] bf16 ----
__global__ __launch_bounds__(256) void im2col_patches(
    const float* __restrict__ X, unsigned short* __restrict__ A) {
  int idx = blockIdx.x * 256 + threadIdx.x;
  if (idx >= NPATCH * Bn * Dn) return;
  int col = idx % Dn, row = idx / Dn;
  int b = row / NPATCH, pi = row % NPATCH;
  int hp = pi / 14, wp = pi % 14;
  int c = col >> 8, r2 = col & 255, p = r2 >> 4, q = r2 & 15;
  A[idx] = f2bf(X[(((size_t)b * 3 + c) * 224 + hp * 16 + p) * 224 + wp * 16 + q]);
}

// ---- x[b][0][:] = cls_token + pos_emb[0] ----
__global__ __launch_bounds__(256) void init_cls(
    const float* __restrict__ cls_tok, const float* __restrict__ pos_emb,
    float* __restrict__ x) {
  int i = blockIdx.x * 256 + threadIdx.x;
  if (i >= Bn * Dn) return;
  int b = i / Dn, d = i % Dn;
  x[(size_t)b * Sn * Dn + d] = cls_tok[d] + pos_emb[d];
}

// ---- pack per-layer qkv biases: bqkv[l][0:768]=bq, [768:1536]=bk, [1536:2304]=bv
__global__ __launch_bounds__(256) void pack_qkv_bias(
    const float* __restrict__ bq, const float* __restrict__ bk,
    const float* __restrict__ bv, float* __restrict__ out) {
  int i = blockIdx.x * 256 + threadIdx.x;
  if (i >= Ln * 3 * Dn) return;
  int l = i / (3 * Dn), r = i % (3 * Dn);
  int which = r / Dn, d = r % Dn;
  const float* src = which == 0 ? bq : (which == 1 ? bk : bv);
  out[i] = src[(size_t)l * Dn + d];
}

// ---- LayerNorm over D=768; out bf16 ----
__global__ __launch_bounds__(256) void layernorm_k(
    const float* __restrict__ x, int row_stride,
    const float* __restrict__ g, const float* __restrict__ b,
    unsigned short* __restrict__ out) {
  int row = blockIdx.x, t = threadIdx.x;
  const float* xr = x + (size_t)row * row_stride;
  float v0 = xr[t], v1 = xr[t + 256], v2 = xr[t + 512];
  float s = v0 + v1 + v2;
  __shared__ float red[4];
  int lane = t & 63, wid = t >> 6;
  for (int off = 32; off > 0; off >>= 1) s += __shfl_xor(s, off, 64);
  if (lane == 0) red[wid] = s;
  __syncthreads();
  float mean = (red[0] + red[1] + red[2] + red[3]) * (1.f / 768.f);
  __syncthreads();
  float d0 = v0 - mean, d1 = v1 - mean, d2 = v2 - mean;
  float q = d0 * d0 + d1 * d1 + d2 * d2;
  for (int off = 32; off > 0; off >>= 1) q += __shfl_xor(q, off, 64);
  if (lane == 0) red[wid] = q;
  __syncthreads();
  float var = (red[0] + red[1] + red[2] + red[3]) * (1.f / 768.f);
  float rstd = rsqrtf(var + 1e-5f);
  size_t o = (size_t)row * Dn;
  out[o + t]       = f2bf(d0 * rstd * g[t]       + b[t]);
  out[o + t + 256] = f2bf(d1 * rstd * g[t + 256] + b[t + 256]);
  out[o + t + 512] = f2bf(d2 * rstd * g[t + 512] + b[t + 512]);
}

// ---- split-K reduce: x[e] = x[e] + bias[n] + sum_kc part[kc][e] ----
__global__ __launch_bounds__(256) void splitk_reduce(
    const float* __restrict__ part, const float* __restrict__ bias,
    float* __restrict__ x, int N, int ks) {
  size_t e = ((size_t)blockIdx.x * 256 + threadIdx.x) * 4;
  if (e >= (size_t)MTOK * N) return;
  f32x4 s = *(const f32x4*)(x + e);
  int gn = (int)(e % N);
  const float* bp = bias + gn;
  s[0] += bp[0]; s[1] += bp[1]; s[2] += bp[2]; s[3] += bp[3];
  for (int kc = 0; kc < ks; kc++) {
    f32x4 p = *(const f32x4*)(part + (size_t)kc * MTOK * N + e);
    s[0] += p[0]; s[1] += p[1]; s[2] += p[2]; s[3] += p[3];
  }
  *(f32x4*)(x + e) = s;
}

// ---- m97-structure MFMA GEMM: 128x128 tile, 4 waves, 4x4 frags/wave,
//      global_load_lds width=16 staging, bijective XCD swizzle, optional split-K.
// C[M][N] = A[M][kstride](bf16, rows padded to 128) * Bt[N][kstride](bf16)^T
// Each block computes K range [kc*KC, (kc+1)*KC); grid.x = ntiles*ksplit.
// Requires: N % 128 == 0, KC % 32 == 0.
// NOTE: epilogue loops MUST be fully unrolled — runtime indexing of acc[][]
// demotes the accumulator to scratch (rule #20; round-2 regression).
// MODE 1: out fp32 [M][N] = acc+bias+res    (residual add, in-place on x ok)
// MODE 2: out bf16 [M][N] = gelu(acc+bias)
// MODE 3: patch: out fp32 x[b][1+pi][n] = acc+bias+pos_emb[(1+pi)*D+n]
// MODE 5: fused qkv: N=2304; Cb=qb base; qb/kb/vb contiguous, MPAD rows each
// MODE 6: split-K partial: Cf[kc][gm][gn] = acc (no bias)
template <int MODE>
__global__ __launch_bounds__(256) void gemm128(
    const unsigned short* __restrict__ A, const unsigned short* __restrict__ Bt,
    const float* __restrict__ bias, const float* __restrict__ res,
    float* __restrict__ Cf, unsigned short* __restrict__ Cb,
    int M, int N, int KC, int kstride, int ksplit, int nbn) {
  __shared__ unsigned short As[128][32];
  __shared__ unsigned short Bs[128][32];
  // bijective XCD swizzle (m204): same-XCD blocks get consecutive work ids
  int nwg = gridDim.x;
  int orig = blockIdx.x;
  int qq = nwg >> 3, rr = nwg & 7;
  int xcd = orig & 7, loc = orig >> 3;
  int wg = (xcd < rr ? xcd * (qq + 1) : rr * (qq + 1) + (xcd - rr) * qq) + loc;
  int ntiles = nwg / ksplit;
  int kc = wg / ntiles;          // K-plane (consecutive wgs share a kc plane)
  int tile = wg - kc * ntiles;
  int mb = tile / nbn, nb = tile % nbn;
  int m0 = mb * 128, n0 = nb * 128;

  int tid = threadIdx.x, wid = tid >> 6, lane = tid & 63;
  int wm = (wid >> 1) * 64, wn = (wid & 1) * 64;
  int lrow = lane & 15, lq = lane >> 4;
  // staging: lane covers As[wid*16 + lane/4][(lane&3)*8 ..+8] (= base+lane*16B)
  int sr = wid * 16 + (lane >> 2);
  int sc = (lane & 3) * 8;
  const unsigned short* Ap = A + (size_t)(m0 + sr) * kstride + (size_t)kc * KC + sc;
  const unsigned short* Bp = Bt + (size_t)(n0 + sr) * kstride + (size_t)kc * KC + sc;

  f32x4 acc[4][4] = {};
  for (int k0 = 0; k0 < KC; k0 += 32) {
    gload16(Ap, &As[wid * 16][0]);
    gload16(Ap + (size_t)64 * kstride, &As[64 + wid * 16][0]);
    gload16(Bp, &Bs[wid * 16][0]);
    gload16(Bp + (size_t)64 * kstride, &Bs[64 + wid * 16][0]);
    Ap += 32; Bp += 32;
    __syncthreads();   // compiler drains vmcnt(0) -> tile ready
    short8 af[4], bfr[4];
#pragma unroll
    for (int tm = 0; tm < 4; tm++)
      af[tm] = *(const short8*)(&As[wm + tm * 16 + lrow][lq * 8]);
#pragma unroll
    for (int tn = 0; tn < 4; tn++)
      bfr[tn] = *(const short8*)(&Bs[wn + tn * 16 + lrow][lq * 8]);
#pragma unroll
    for (int tm = 0; tm < 4; tm++)
#pragma unroll
      for (int tn = 0; tn < 4; tn++)
        acc[tm][tn] = __builtin_amdgcn_mfma_f32_16x16x32_bf16(
            af[tm], bfr[tn], acc[tm][tn], 0, 0, 0);
    __syncthreads();   // all waves done reading before next overwrite
  }

#pragma unroll
  for (int tm = 0; tm < 4; tm++)
#pragma unroll
    for (int tn = 0; tn < 4; tn++)
#pragma unroll
      for (int r = 0; r < 4; r++) {
        int gm = m0 + wm + tm * 16 + lq * 4 + r;
        int gn = n0 + wn + tn * 16 + lrow;
        if (gm >= M || gn >= N) continue;
        float val;
        if constexpr (MODE == 6) val = acc[tm][tn][r];
        else val = acc[tm][tn][r] + bias[gn];
        if constexpr (MODE == 1) {
          size_t o = (size_t)gm * N + gn;
          Cf[o] = val + res[o];
        } else if constexpr (MODE == 2) {
          float gl = 0.5f * val * (1.f + erff(val * 0.70710678118654752f));
          Cb[(size_t)gm * N + gn] = f2bf(gl);
        } else if constexpr (MODE == 3) {
          int b = gm / NPATCH, pi = gm % NPATCH;
          Cf[((size_t)b * Sn + 1 + pi) * Dn + gn] =
              val + res[(size_t)(1 + pi) * Dn + gn];
        } else if constexpr (MODE == 5) {
          int which = gn / Dn;            // 0=q 1=k 2=v
          int d = gn - which * Dn;
          int b = gm / Sn, s = gm % Sn;
          int h = d >> 6, dh = d & 63;
          Cb[(size_t)which * MPAD * Dn +
             (((size_t)b * Hn + h) * Sn + s) * DHn + dh] = f2bf(val);
        } else if constexpr (MODE == 6) {
          Cf[((size_t)kc * MTOK + gm) * N + gn] = val;
        }
      }
}

// ---- small-M GEMM for the classifier head (N=1000 not mult of 128) ----
// MODE 4: out fp32 [M][N] = acc+bias
template <int MODE>
__global__ __launch_bounds__(256) void gemm64(
    const unsigned short* __restrict__ A, const unsigned short* __restrict__ Bt,
    const float* __restrict__ bias, const float* __restrict__ res,
    float* __restrict__ Cf, unsigned short* __restrict__ Cb,
    int M, int N, int K) {
  __shared__ unsigned short As[64][32];
  __shared__ unsigned short Bs[64][32];
  int m0 = blockIdx.x * 64, n0 = blockIdx.y * 64;
  int tid = threadIdx.x;
  int wid = tid >> 6, lane = tid & 63;
  int wm = (wid >> 1) * 32, wn = (wid & 1) * 32;
  int lrow = lane & 15, lq = lane >> 4;
  int lr = tid >> 2, lseg = (tid & 3) * 8;
  f32x4 acc[2][2] = {};
  for (int k0 = 0; k0 < K; k0 += 32) {
    int gm = m0 + lr;
    uint4 av = (gm < M) ? *(const uint4*)(A + (size_t)gm * K + k0 + lseg)
                        : make_uint4(0, 0, 0, 0);
    int gn = n0 + lr;
    uint4 bv = (gn < N) ? *(const uint4*)(Bt + (size_t)gn * K + k0 + lseg)
                        : make_uint4(0, 0, 0, 0);
    __syncthreads();
    *(uint4*)(&As[lr][lseg]) = av;
    *(uint4*)(&Bs[lr][lseg]) = bv;
    __syncthreads();
    short8 a0 = *(const short8*)(&As[wm + lrow][lq * 8]);
    short8 a1 = *(const short8*)(&As[wm + 16 + lrow][lq * 8]);
    short8 b0 = *(const short8*)(&Bs[wn + lrow][lq * 8]);
    short8 b1 = *(const short8*)(&Bs[wn + 16 + lrow][lq * 8]);
    acc[0][0] = __builtin_amdgcn_mfma_f32_16x16x32_bf16(a0, b0, acc[0][0], 0, 0, 0);
    acc[0][1] = __builtin_amdgcn_mfma_f32_16x16x32_bf16(a0, b1, acc[0][1], 0, 0, 0);
    acc[1][0] = __builtin_amdgcn_mfma_f32_16x16x32_bf16(a1, b0, acc[1][0], 0, 0, 0);
    acc[1][1] = __builtin_amdgcn_mfma_f32_16x16x32_bf16(a1, b1, acc[1][1], 0, 0, 0);
  }
#pragma unroll
  for (int tm = 0; tm < 2; tm++)
#pragma unroll
    for (int tn = 0; tn < 2; tn++)
#pragma unroll
      for (int r = 0; r < 4; r++) {
        int ml = wm + tm * 16 + lq * 4 + r;
        int nl = wn + tn * 16 + lrow;
        int gm = m0 + ml, gn = n0 + nl;
        if (gm >= M || gn >= N) continue;
        float val = acc[tm][tn][r] + bias[gn];
        if constexpr (MODE == 4) {
          Cf[(size_t)gm * N + gn] = val;
        }
      }
}

// ---- MFMA flash-style attention (unchanged) ----
#define QT 16
#define NKT 13        // ceil(197/16)
#define PJ 232        // padded j extent
__global__ __launch_bounds__(256) void attn_mfma(
    const unsigned short* __restrict__ q, const unsigned short* __restrict__ k,
    const unsigned short* __restrict__ v, unsigned short* __restrict__ out) {
  int bh = blockIdx.x, b = bh / Hn, h = bh % Hn;
  const unsigned short* qp = q + (size_t)bh * Sn * DHn;
  const unsigned short* kp = k + (size_t)bh * Sn * DHn;
  const unsigned short* vp = v + (size_t)bh * Sn * DHn;
  __shared__ unsigned short Vt[DHn][PJ];      // 64 x 232 bf16 = 29 KB
  __shared__ unsigned short Pl[4][QT][PJ];    // per-wave P,   = 29 KB
  int t = threadIdx.x, lane = t & 63, wid = t >> 6;
  int col = lane & 15, quad = lane >> 4;

  for (int i = t; i < Sn * DHn; i += 256) {
    int j = i >> 6, d = i & 63;
    Vt[d][j] = vp[i];
  }
  for (int i = t; i < DHn * (PJ - Sn); i += 256) {
    int d = i / (PJ - Sn), j = Sn + i % (PJ - Sn);
    Vt[d][j] = 0;
  }
  for (int i = lane; i < QT * (PJ - NKT * 16); i += 64) {
    int r = i / (PJ - NKT * 16), c = NKT * 16 + i % (PJ - NKT * 16);
    Pl[wid][r][c] = 0;
  }
  __syncthreads();

  for (int qt = wid; qt < NKT; qt += 4) {
    int q0 = qt * QT;
    int qrow = q0 + col;
    int qc = (qrow < Sn) ? qrow : (Sn - 1);
    short8 qa0 = *(const short8*)(qp + (size_t)qc * DHn + quad * 8);
    short8 qa1 = *(const short8*)(qp + (size_t)qc * DHn + 32 + quad * 8);

    f32x4 sc[NKT];
    for (int kt = 0; kt < NKT; kt++) {
      int krow = kt * QT + col;
      int kc = (krow < Sn) ? krow : (Sn - 1);
      short8 kb0 = *(const short8*)(kp + (size_t)kc * DHn + quad * 8);
      short8 kb1 = *(const short8*)(kp + (size_t)kc * DHn + 32 + quad * 8);
      f32x4 c = {};
      c = __builtin_amdgcn_mfma_f32_16x16x32_bf16(qa0, kb0, c, 0, 0, 0);
      c = __builtin_amdgcn_mfma_f32_16x16x32_bf16(qa1, kb1, c, 0, 0, 0);
      if (krow >= Sn)
        for (int r = 0; r < 4; r++) c[r] = -1e30f;
      sc[kt] = c;
    }

    for (int r = 0; r < 4; r++) {
      float m = -1e30f;
      for (int kt = 0; kt < NKT; kt++) m = fmaxf(m, sc[kt][r]);
      for (int off = 1; off < 16; off <<= 1) m = fmaxf(m, __shfl_xor(m, off, 64));
      float s = 0.f;
      for (int kt = 0; kt < NKT; kt++) {
        float e = __expf((sc[kt][r] - m) * 0.125f);
        sc[kt][r] = e;
        s += e;
      }
      for (int off = 1; off < 16; off <<= 1) s += __shfl_xor(s, off, 64);
      float inv = 1.f / s;
      int row = quad * 4 + r;
      for (int kt = 0; kt < NKT; kt++)
        Pl[wid][row][kt * 16 + col] = f2bf(sc[kt][r] * inv);
    }

    f32x4 o[4] = {};
    for (int jc = 0; jc < 7; jc++) {
      short8 pa = *(const short8*)(&Pl[wid][col][jc * 32 + quad * 8]);
      for (int dt = 0; dt < 4; dt++) {
        short8 vb = *(const short8*)(&Vt[dt * 16 + col][jc * 32 + quad * 8]);
        o[dt] = __builtin_amdgcn_mfma_f32_16x16x32_bf16(pa, vb, o[dt], 0, 0, 0);
      }
    }

    for (int dt = 0; dt < 4; dt++)
      for (int r = 0; r < 4; r++) {
        int qq = q0 + quad * 4 + r;
        if (qq < Sn)
          out[((size_t)b * Sn + qq) * Dn + h * DHn + dt * 16 + col] =
              f2bf(o[dt][r]);
      }
  }
}

extern "C" void kernel_launch(void* const* d_in, const int* in_sizes, int n_in,
                              void* d_out, int out_size, void* d_ws, size_t ws_size,
                              hipStream_t stream) {
  const float* X       = (const float*)d_in[0];
  const float* patch_w = (const float*)d_in[1];
  const float* patch_b = (const float*)d_in[2];
  const float* cls_tok = (const float*)d_in[3];
  const float* pos_emb = (const float*)d_in[4];
  const float* ln1_g = (const float*)d_in[5];
  const float* ln1_b = (const float*)d_in[6];
  const float* Wq = (const float*)d_in[7];
  const float* bq = (const float*)d_in[8];
  const float* Wk = (const float*)d_in[9];
  const float* bk = (const float*)d_in[10];
  const float* Wv = (const float*)d_in[11];
  const float* bv = (const float*)d_in[12];
  const float* Wo = (const float*)d_in[13];
  const float* bo = (const float*)d_in[14];
  const float* ln2_g = (const float*)d_in[15];
  const float* ln2_b = (const float*)d_in[16];
  const float* Wf1 = (const float*)d_in[17];
  const float* bf1 = (const float*)d_in[18];
  const float* Wf2 = (const float*)d_in[19];
  const float* bf2 = (const float*)d_in[20];
  const float* lnf_g = (const float*)d_in[21];
  const float* lnf_b = (const float*)d_in[22];
  const float* head_w = (const float*)d_in[23];
  const float* head_b = (const float*)d_in[24];
  float* out = (float*)d_out;

  char* base = (char*)d_ws;
  size_t off = 0;
  auto alloc = [&](size_t bytes) -> void* {
    void* p = base + off;
    off += (bytes + 255) & ~(size_t)255;
    return p;
  };
  // NOTE: wq_t/wk_t/wv_t must stay consecutive (fused QKV Bt = [2304][768]);
  // qb/kb/vb must stay consecutive with MPAD*Dn stride (fused QKV epilogue).
  unsigned short* wq_t  = (unsigned short*)alloc((size_t)Dn * Dn * 2);
  unsigned short* wk_t  = (unsigned short*)alloc((size_t)Dn * Dn * 2);
  unsigned short* wv_t  = (unsigned short*)alloc((size_t)Dn * Dn * 2);
  unsigned short* wo_t  = (unsigned short*)alloc((size_t)Dn * Dn * 2);
  unsigned short* wf1_t = (unsigned short*)alloc((size_t)Dn * Fn * 2);
  unsigned short* wf2_t = (unsigned short*)alloc((size_t)Dn * Fn * 2);
  unsigned short* pw_bf = (unsigned short*)alloc((size_t)Dn * Dn * 2);
  unsigned short* hw_t  = (unsigned short*)alloc((size_t)NCLSn * Dn * 2);
  unsigned short* im2c  = (unsigned short*)alloc((size_t)MPAD * Dn * 2);
  float*          x     = (float*)alloc((size_t)MTOK * Dn * 4);
  unsigned short* h_bf  = (unsigned short*)alloc((size_t)MPAD * Dn * 2);
  unsigned short* qb    = (unsigned short*)alloc((size_t)MPAD * Dn * 2);
  unsigned short* kb    = (unsigned short*)alloc((size_t)MPAD * Dn * 2);
  unsigned short* vb    = (unsigned short*)alloc((size_t)MPAD * Dn * 2);
  unsigned short* atob  = (unsigned short*)alloc((size_t)MPAD * Dn * 2);
  unsigned short* gel   = (unsigned short*)alloc((size_t)MPAD * Fn * 2);
  unsigned short* clsb  = (unsigned short*)alloc((size_t)Bn * Dn * 2);
  float*          bqkv  = (float*)alloc((size_t)Ln * 3 * Dn * 4);
  (void)in_sizes; (void)n_in; (void)out_size;

  // optional split-K partial planes (4 x [MTOK][Dn] fp32 = 77.5 MB)
  const size_t SZ_PART = (size_t)4 * MTOK * Dn * 4;
  float* part = nullptr;
  if (off + SZ_PART + 4096 <= ws_size) part = (float*)alloc(SZ_PART);
  // optional hoisted all-layer transposed weights (~170 MB)
  const size_t SZ_QKV = (size_t)Ln * 3 * Dn * Dn * 2;
  const size_t SZ_WO  = (size_t)Ln * Dn * Dn * 2;
  const size_t SZ_WF  = (size_t)Ln * Dn * Fn * 2;
  unsigned short *wqkv_all = nullptr, *wo_all = nullptr,
                 *wf1_all = nullptr, *wf2_all = nullptr;
  if (off + SZ_QKV + SZ_WO + 2 * SZ_WF + 8192 <= ws_size) {
    wqkv_all = (unsigned short*)alloc(SZ_QKV);
    wo_all   = (unsigned short*)alloc(SZ_WO);
    wf1_all  = (unsigned short*)alloc(SZ_WF);
    wf2_all  = (unsigned short*)alloc(SZ_WF);
  }
  const bool sk = part != nullptr;
  const bool hoist = wqkv_all != nullptr;

  dim3 tb(32, 8);
  auto tgrid = [](int rows, int cols) { return dim3((cols + 31) / 32, (rows + 31) / 32); };
  auto g128 = [](int M, int N, int ks) {
    return dim3((unsigned)(((M + 127) / 128) * ((N + 127) / 128) * ks));
  };

  // prologue
  cast_bf<<<(Dn * Dn + 255) / 256, 256, 0, stream>>>(patch_w, pw_bf, Dn * Dn);
  transpose_cast<<<tgrid(Dn, NCLSn), tb, 0, stream>>>(head_w, hw_t, Dn, NCLSn);
  pack_qkv_bias<<<(Ln * 3 * Dn + 255) / 256, 256, 0, stream>>>(bq, bk, bv, bqkv);
  im2col_patches<<<(Bn * NPATCH * Dn + 255) / 256, 256, 0, stream>>>(X, im2c);
  init_cls<<<(Bn * Dn + 255) / 256, 256, 0, stream>>>(cls_tok, pos_emb, x);
  gemm128<3><<<g128(Bn * NPATCH, Dn, 1), 256, 0, stream>>>(
      im2c, pw_bf, patch_b, pos_emb, x, nullptr, Bn * NPATCH, Dn, Dn, Dn, 1, Dn / 128);

  if (hoist) {  // all-layer weight transposes, batched over z = layer
    dim3 z88(24, 24, Ln);
    transpose_cast_b<<<z88, tb, 0, stream>>>(
        Wq, wqkv_all, Dn, Dn, (size_t)Dn * Dn, (size_t)3 * Dn * Dn, 0);
    transpose_cast_b<<<z88, tb, 0, stream>>>(
        Wk, wqkv_all, Dn, Dn, (size_t)Dn * Dn, (size_t)3 * Dn * Dn, Dn);
    transpose_cast_b<<<z88, tb, 0, stream>>>(
        Wv, wqkv_all, Dn, Dn, (size_t)Dn * Dn, (size_t)3 * Dn * Dn, 2 * Dn);
    transpose_cast_b<<<z88, tb, 0, stream>>>(
        Wo, wo_all, Dn, Dn, (size_t)Dn * Dn, (size_t)Dn * Dn, 0);
    transpose_cast_b<<<dim3(96, 24, Ln), tb, 0, stream>>>(
        Wf1, wf1_all, Dn, Fn, (size_t)Dn * Fn, (size_t)Fn * Dn, 0);
    transpose_cast_b<<<dim3(24, 96, Ln), tb, 0, stream>>>(
        Wf2, wf2_all, Fn, Dn, (size_t)Fn * Dn, (size_t)Dn * Fn, 0);
  }

  for (int l = 0; l < Ln; l++) {
    const size_t wo_off = (size_t)l * Dn * Dn;
    const size_t wf_off = (size_t)l * Dn * Fn;
    const unsigned short* wqkv_l = hoist ? wqkv_all + (size_t)l * 3 * Dn * Dn : wq_t;
    const unsigned short* wo_l   = hoist ? wo_all + wo_off : wo_t;
    const unsigned short* wf1_l  = hoist ? wf1_all + wf_off : wf1_t;
    const unsigned short* wf2_l  = hoist ? wf2_all + wf_off : wf2_t;
    if (!hoist) {
      transpose_cast<<<tgrid(Dn, Dn), tb, 0, stream>>>(Wq + wo_off, wq_t, Dn, Dn);
      transpose_cast<<<tgrid(Dn, Dn), tb, 0, stream>>>(Wk + wo_off, wk_t, Dn, Dn);
      transpose_cast<<<tgrid(Dn, Dn), tb, 0, stream>>>(Wv + wo_off, wv_t, Dn, Dn);
      transpose_cast<<<tgrid(Dn, Dn), tb, 0, stream>>>(Wo + wo_off, wo_t, Dn, Dn);
      transpose_cast<<<tgrid(Dn, Fn), tb, 0, stream>>>(Wf1 + wf_off, wf1_t, Dn, Fn);
      transpose_cast<<<tgrid(Fn, Dn), tb, 0, stream>>>(Wf2 + wf_off, wf2_t, Fn, Dn);
    }

    layernorm_k<<<MTOK, 256, 0, stream>>>(x, Dn, ln1_g + (size_t)l * Dn,
                                          ln1_b + (size_t)l * Dn, h_bf);
    // fused QKV: Bt = [wq|wk|wv]^T contiguous = [2304][768]
    gemm128<5><<<g128(MTOK, 3 * Dn, 1), 256, 0, stream>>>(
        h_bf, wqkv_l, bqkv + (size_t)l * 3 * Dn, nullptr, nullptr, qb,
        MTOK, 3 * Dn, Dn, Dn, 1, 3 * Dn / 128);
    attn_mfma<<<Bn * Hn, 256, 0, stream>>>(qb, kb, vb, atob);
    if (sk) {  // Wo projection, split-K x2 (grid 300 -> 600 blocks)
      gemm128<6><<<g128(MTOK, Dn, 2), 256, 0, stream>>>(
          atob, wo_l, nullptr, nullptr, part, nullptr,
          MTOK, Dn, Dn / 2, Dn, 2, Dn / 128);
      splitk_reduce<<<(MTOK * Dn / 4 + 255) / 256, 256, 0, stream>>>(
          part, bo + (size_t)l * Dn, x, Dn, 2);
    } else {
      gemm128<1><<<g128(MTOK, Dn, 1), 256, 0, stream>>>(
          atob, wo_l, bo + (size_t)l * Dn, x, x, nullptr, MTOK, Dn, Dn, Dn, 1, Dn / 128);
    }
    layernorm_k<<<MTOK, 256, 0, stream>>>(x, Dn, ln2_g + (size_t)l * Dn,
                                          ln2_b + (size_t)l * Dn, h_bf);
    gemm128<2><<<g128(MTOK, Fn, 1), 256, 0, stream>>>(
        h_bf, wf1_l, bf1 + (size_t)l * Fn, nullptr, nullptr, gel,
        MTOK, Fn, Dn, Dn, 1, Fn / 128);
    if (sk) {  // FF2, split-K x4 (grid 300 -> 1200 blocks)
      gemm128<6><<<g128(MTOK, Dn, 4), 256, 0, stream>>>(
          gel, wf2_l, nullptr, nullptr, part, nullptr,
          MTOK, Dn, Fn / 4, Fn, 4, Dn / 128);
      splitk_reduce<<<(MTOK * Dn / 4 + 255) / 256, 256, 0, stream>>>(
          part, bf2 + (size_t)l * Dn, x, Dn, 4);
    } else {
      gemm128<1><<<g128(MTOK, Dn, 1), 256, 0, stream>>>(
          gel, wf2_l, bf2 + (size_t)l * Dn, x, x, nullptr, MTOK, Dn, Fn, Fn, 1, Dn / 128);
    }
  }

  layernorm_k<<<Bn, 256, 0, stream>>>(x, Sn * Dn, lnf_g, lnf_b, clsb);
  gemm64<4><<<dim3(1, (NCLSn + 63) / 64), 256, 0, stream>>>(
      clsb, hw_t, head_b, nullptr, out, nullptr, Bn, NCLSn, Dn);
}

// Round 6
// 3676.067 us; speedup vs baseline: 4.5444x; 1.0705x over previous
//
#include <hip/hip_runtime.h>
#include <math.h>

// ---- problem constants ----
#define Bn 32
#define Sn 197
#define Dn 768
#define Hn 12
#define DHn 64
#define Fn 3072
#define Ln 12
#define NPATCH 196
#define NCLSn 1000
#define MTOK (Bn * Sn)   // 6304
#define MPAD 6400        // MTOK padded to multiple of 128 (gemm128 staging reads)

typedef __attribute__((ext_vector_type(8))) short short8;
typedef __attribute__((ext_vector_type(4))) float f32x4;

__device__ __forceinline__ unsigned short f2bf(float f) {
  union { float f; unsigned int u; } v; v.f = f;
  unsigned int r = v.u + 0x7fffu + ((v.u >> 16) & 1u);
  return (unsigned short)(r >> 16);
}
__device__ __forceinline__ float bf2f(unsigned short h) {
  union { unsigned int u; float f; } v; v.u = ((unsigned int)h) << 16;
  return v.f;
}

// direct HBM -> LDS DMA, 16B per lane (dest = wave-uniform base + lane*16)
__device__ __forceinline__ void gload16(const unsigned short* g, unsigned short* l) {
  __builtin_amdgcn_global_load_lds(
      (const __attribute__((address_space(1))) unsigned int*)g,
      (__attribute__((address_space(3))) unsigned int*)l, 16, 0, 0);
}

// ---- transpose + cast fp32[rows][cols] -> bf16[cols][rows] ----
__global__ __launch_bounds__(256) void transpose_cast(
    const float* __restrict__ in, unsigned short* __restrict__ out,
    int rows, int cols) {
  __shared__ float tile[32][33];
  int c0 = blockIdx.x * 32, r0 = blockIdx.y * 32;
  int tx = threadIdx.x, ty = threadIdx.y;
  for (int i = 0; i < 32; i += 8) {
    int r = r0 + ty + i, c = c0 + tx;
    tile[ty + i][tx] = (r < rows && c < cols) ? in[(size_t)r * cols + c] : 0.f;
  }
  __syncthreads();
  for (int i = 0; i < 32; i += 8) {
    int c = c0 + ty + i, r = r0 + tx;
    if (c < cols && r < rows)
      out[(size_t)c * rows + r] = f2bf(tile[tx][ty + i]);
  }
}

// ---- batched (z = layer) transpose+cast; writes out[(c+coff)*rows + r] ----
__global__ __launch_bounds__(256) void transpose_cast_b(
    const float* __restrict__ in, unsigned short* __restrict__ out,
    int rows, int cols, size_t in_ls, size_t out_ls, int coff) {
  __shared__ float tile[32][33];
  int l = blockIdx.z;
  in += (size_t)l * in_ls;
  out += (size_t)l * out_ls;
  int c0 = blockIdx.x * 32, r0 = blockIdx.y * 32;
  int tx = threadIdx.x, ty = threadIdx.y;
  for (int i = 0; i < 32; i += 8) {
    int r = r0 + ty + i, c = c0 + tx;
    tile[ty + i][tx] = (r < rows && c < cols) ? in[(size_t)r * cols + c] : 0.f;
  }
  __syncthreads();
  for (int i = 0; i < 32; i += 8) {
    int c = c0 + ty + i, r = r0 + tx;
    if (c < cols && r < rows)
      out[(size_t)(c + coff) * rows + r] = f2bf(tile[tx][ty + i]);
  }
}

// ---- plain cast fp32 -> bf16 ----
__global__ __launch_bounds__(256) void cast_bf(
    const float* __restrict__ in, unsigned short* __restrict__ out, int n) {
  int i = blockIdx.x * 256 + threadIdx.x;
  if (i < n) out[i] = f2bf(in[i]);
}

// ---- im2col: X[B,3,224,224] -> A[b*196+hp*14+wp][c*256+p*16+q] bf16 ----
__global__ __launch_bounds__(256) void im2col_patches(
    const float* __restrict__ X, unsigned short* __restrict__ A) {
  int idx = blockIdx.x * 256 + threadIdx.x;
  if (idx >= NPATCH * Bn * Dn) return;
  int col = idx % Dn, row = idx / Dn;
  int b = row / NPATCH, pi = row % NPATCH;
  int hp = pi / 14, wp = pi % 14;
  int c = col >> 8, r2 = col & 255, p = r2 >> 4, q = r2 & 15;
  A[idx] = f2bf(X[(((size_t)b * 3 + c) * 224 + hp * 16 + p) * 224 + wp * 16 + q]);
}

// ---- x[b][0][:] = cls_token + pos_emb[0] ----
__global__ __launch_bounds__(256) void init_cls(
    const float* __restrict__ cls_tok, const float* __restrict__ pos_emb,
    float* __restrict__ x) {
  int i = blockIdx.x * 256 + threadIdx.x;
  if (i >= Bn * Dn) return;
  int b = i / Dn, d = i % Dn;
  x[(size_t)b * Sn * Dn + d] = cls_tok[d] + pos_emb[d];
}

// ---- pack per-layer qkv biases: bqkv[l][0:768]=bq, [768:1536]=bk, [1536:2304]=bv
__global__ __launch_bounds__(256) void pack_qkv_bias(
    const float* __restrict__ bq, const float* __restrict__ bk,
    const float* __restrict__ bv, float* __restrict__ out) {
  int i = blockIdx.x * 256 + threadIdx.x;
  if (i >= Ln * 3 * Dn) return;
  int l = i / (3 * Dn), r = i % (3 * Dn);
  int which = r / Dn, d = r % Dn;
  const float* src = which == 0 ? bq : (which == 1 ? bk : bv);
  out[i] = src[(size_t)l * Dn + d];
}

// ---- LayerNorm over D=768; out bf16 ----
__global__ __launch_bounds__(256) void layernorm_k(
    const float* __restrict__ x, int row_stride,
    const float* __restrict__ g, const float* __restrict__ b,
    unsigned short* __restrict__ out) {
  int row = blockIdx.x, t = threadIdx.x;
  const float* xr = x + (size_t)row * row_stride;
  float v0 = xr[t], v1 = xr[t + 256], v2 = xr[t + 512];
  float s = v0 + v1 + v2;
  __shared__ float red[4];
  int lane = t & 63, wid = t >> 6;
  for (int off = 32; off > 0; off >>= 1) s += __shfl_xor(s, off, 64);
  if (lane == 0) red[wid] = s;
  __syncthreads();
  float mean = (red[0] + red[1] + red[2] + red[3]) * (1.f / 768.f);
  __syncthreads();
  float d0 = v0 - mean, d1 = v1 - mean, d2 = v2 - mean;
  float q = d0 * d0 + d1 * d1 + d2 * d2;
  for (int off = 32; off > 0; off >>= 1) q += __shfl_xor(q, off, 64);
  if (lane == 0) red[wid] = q;
  __syncthreads();
  float var = (red[0] + red[1] + red[2] + red[3]) * (1.f / 768.f);
  float rstd = rsqrtf(var + 1e-5f);
  size_t o = (size_t)row * Dn;
  out[o + t]       = f2bf(d0 * rstd * g[t]       + b[t]);
  out[o + t + 256] = f2bf(d1 * rstd * g[t + 256] + b[t + 256]);
  out[o + t + 512] = f2bf(d2 * rstd * g[t + 512] + b[t + 512]);
}

// ---- split-K reduce: x[e] = x[e] + bias[n] + sum_kc part[kc][e] ----
__global__ __launch_bounds__(256) void splitk_reduce(
    const float* __restrict__ part, const float* __restrict__ bias,
    float* __restrict__ x, int N, int ks) {
  size_t e = ((size_t)blockIdx.x * 256 + threadIdx.x) * 4;
  if (e >= (size_t)MTOK * N) return;
  f32x4 s = *(const f32x4*)(x + e);
  int gn = (int)(e % N);
  const float* bp = bias + gn;
  s[0] += bp[0]; s[1] += bp[1]; s[2] += bp[2]; s[3] += bp[3];
  for (int kc = 0; kc < ks; kc++) {
    f32x4 p = *(const f32x4*)(part + (size_t)kc * MTOK * N + e);
    s[0] += p[0]; s[1] += p[1]; s[2] += p[2]; s[3] += p[3];
  }
  *(f32x4*)(x + e) = s;
}

// ---- m97-structure MFMA GEMM + T3 2-phase double-buffered prefetch.
// 128x128 tile, 4 waves, 4x4 frags/wave, global_load_lds width=16 staging,
// bijective XCD swizzle, optional split-K.
// K-loop: stage tile t+1 into alternate LDS buffer BEFORE computing tile t;
// single __syncthreads()/step (compiler drains vmcnt(0) at the barrier) so
// HBM latency hides under the current tile's ds_read+MFMA. Race-safety:
// reads of buf X at step t-1 are register-complete before that step's
// barrier, so staging into X at step t cannot clobber live reads.
// C[M][N] = A[M][kstride](bf16, rows padded to 128) * Bt[N][kstride](bf16)^T
// Requires: N % 128 == 0, KC % 32 == 0.
// NOTE: epilogue loops MUST be fully unrolled — runtime indexing of acc[][]
// demotes the accumulator to scratch (rule #20; round-2 regression).
// MODE 1: out fp32 [M][N] = acc+bias+res    (residual add, in-place on x ok)
// MODE 2: out bf16 [M][N] = gelu(acc+bias)
// MODE 3: patch: out fp32 x[b][1+pi][n] = acc+bias+pos_emb[(1+pi)*D+n]
// MODE 5: fused qkv: N=2304; Cb=qb base; qb/kb/vb contiguous, MPAD rows each
// MODE 6: split-K partial: Cf[kc][gm][gn] = acc (no bias)
template <int MODE>
__global__ __launch_bounds__(256, 3) void gemm128(
    const unsigned short* __restrict__ A, const unsigned short* __restrict__ Bt,
    const float* __restrict__ bias, const float* __restrict__ res,
    float* __restrict__ Cf, unsigned short* __restrict__ Cb,
    int M, int N, int KC, int kstride, int ksplit, int nbn) {
  __shared__ unsigned short As[2][128][32];   // 16 KB x2
  __shared__ unsigned short Bs[2][128][32];
  // bijective XCD swizzle (m204): same-XCD blocks get consecutive work ids
  int nwg = gridDim.x;
  int orig = blockIdx.x;
  int qq = nwg >> 3, rr = nwg & 7;
  int xcd = orig & 7, loc = orig >> 3;
  int wg = (xcd < rr ? xcd * (qq + 1) : rr * (qq + 1) + (xcd - rr) * qq) + loc;
  int ntiles = nwg / ksplit;
  int kc = wg / ntiles;          // K-plane (consecutive wgs share a kc plane)
  int tile = wg - kc * ntiles;
  int mb = tile / nbn, nb = tile % nbn;
  int m0 = mb * 128, n0 = nb * 128;

  int tid = threadIdx.x, wid = tid >> 6, lane = tid & 63;
  int wm = (wid >> 1) * 64, wn = (wid & 1) * 64;
  int lrow = lane & 15, lq = lane >> 4;
  // staging: lane covers As[.][wid*16 + lane/4][(lane&3)*8 ..+8]
  int sr = wid * 16 + (lane >> 2);
  int sc = (lane & 3) * 8;
  const unsigned short* Ap = A + (size_t)(m0 + sr) * kstride + (size_t)kc * KC + sc;
  const unsigned short* Bp = Bt + (size_t)(n0 + sr) * kstride + (size_t)kc * KC + sc;
  const int nt = KC >> 5;

  auto stage = [&](int b) {
    gload16(Ap, &As[b][wid * 16][0]);
    gload16(Ap + (size_t)64 * kstride, &As[b][64 + wid * 16][0]);
    gload16(Bp, &Bs[b][wid * 16][0]);
    gload16(Bp + (size_t)64 * kstride, &Bs[b][64 + wid * 16][0]);
    Ap += 32; Bp += 32;
  };

  f32x4 acc[4][4] = {};
  stage(0);
  __syncthreads();               // vmcnt(0) drained at barrier: tile 0 resident
  int cur = 0;
  for (int t = 0; t < nt; ++t) {
    if (t + 1 < nt) stage(cur ^ 1);   // async prefetch of next tile
    short8 af[4], bfr[4];
#pragma unroll
    for (int tm = 0; tm < 4; tm++)
      af[tm] = *(const short8*)(&As[cur][wm + tm * 16 + lrow][lq * 8]);
#pragma unroll
    for (int tn = 0; tn < 4; tn++)
      bfr[tn] = *(const short8*)(&Bs[cur][wn + tn * 16 + lrow][lq * 8]);
#pragma unroll
    for (int tm = 0; tm < 4; tm++)
#pragma unroll
      for (int tn = 0; tn < 4; tn++)
        acc[tm][tn] = __builtin_amdgcn_mfma_f32_16x16x32_bf16(
            af[tm], bfr[tn], acc[tm][tn], 0, 0, 0);
    __syncthreads();             // next tile landed; all reads of cur done
    cur ^= 1;
  }

#pragma unroll
  for (int tm = 0; tm < 4; tm++)
#pragma unroll
    for (int tn = 0; tn < 4; tn++)
#pragma unroll
      for (int r = 0; r < 4; r++) {
        int gm = m0 + wm + tm * 16 + lq * 4 + r;
        int gn = n0 + wn + tn * 16 + lrow;
        if (gm >= M || gn >= N) continue;
        float val;
        if constexpr (MODE == 6) val = acc[tm][tn][r];
        else val = acc[tm][tn][r] + bias[gn];
        if constexpr (MODE == 1) {
          size_t o = (size_t)gm * N + gn;
          Cf[o] = val + res[o];
        } else if constexpr (MODE == 2) {
          float gl = 0.5f * val * (1.f + erff(val * 0.70710678118654752f));
          Cb[(size_t)gm * N + gn] = f2bf(gl);
        } else if constexpr (MODE == 3) {
          int b = gm / NPATCH, pi = gm % NPATCH;
          Cf[((size_t)b * Sn + 1 + pi) * Dn + gn] =
              val + res[(size_t)(1 + pi) * Dn + gn];
        } else if constexpr (MODE == 5) {
          int which = gn / Dn;            // 0=q 1=k 2=v
          int d = gn - which * Dn;
          int b = gm / Sn, s = gm % Sn;
          int h = d >> 6, dh = d & 63;
          Cb[(size_t)which * MPAD * Dn +
             (((size_t)b * Hn + h) * Sn + s) * DHn + dh] = f2bf(val);
        } else if constexpr (MODE == 6) {
          Cf[((size_t)kc * MTOK + gm) * N + gn] = val;
        }
      }
}

// ---- small-M GEMM for the classifier head (N=1000 not mult of 128) ----
// MODE 4: out fp32 [M][N] = acc+bias
template <int MODE>
__global__ __launch_bounds__(256) void gemm64(
    const unsigned short* __restrict__ A, const unsigned short* __restrict__ Bt,
    const float* __restrict__ bias, const float* __restrict__ res,
    float* __restrict__ Cf, unsigned short* __restrict__ Cb,
    int M, int N, int K) {
  __shared__ unsigned short As[64][32];
  __shared__ unsigned short Bs[64][32];
  int m0 = blockIdx.x * 64, n0 = blockIdx.y * 64;
  int tid = threadIdx.x;
  int wid = tid >> 6, lane = tid & 63;
  int wm = (wid >> 1) * 32, wn = (wid & 1) * 32;
  int lrow = lane & 15, lq = lane >> 4;
  int lr = tid >> 2, lseg = (tid & 3) * 8;
  f32x4 acc[2][2] = {};
  for (int k0 = 0; k0 < K; k0 += 32) {
    int gm = m0 + lr;
    uint4 av = (gm < M) ? *(const uint4*)(A + (size_t)gm * K + k0 + lseg)
                        : make_uint4(0, 0, 0, 0);
    int gn = n0 + lr;
    uint4 bv = (gn < N) ? *(const uint4*)(Bt + (size_t)gn * K + k0 + lseg)
                        : make_uint4(0, 0, 0, 0);
    __syncthreads();
    *(uint4*)(&As[lr][lseg]) = av;
    *(uint4*)(&Bs[lr][lseg]) = bv;
    __syncthreads();
    short8 a0 = *(const short8*)(&As[wm + lrow][lq * 8]);
    short8 a1 = *(const short8*)(&As[wm + 16 + lrow][lq * 8]);
    short8 b0 = *(const short8*)(&Bs[wn + lrow][lq * 8]);
    short8 b1 = *(const short8*)(&Bs[wn + 16 + lrow][lq * 8]);
    acc[0][0] = __builtin_amdgcn_mfma_f32_16x16x32_bf16(a0, b0, acc[0][0], 0, 0, 0);
    acc[0][1] = __builtin_amdgcn_mfma_f32_16x16x32_bf16(a0, b1, acc[0][1], 0, 0, 0);
    acc[1][0] = __builtin_amdgcn_mfma_f32_16x16x32_bf16(a1, b0, acc[1][0], 0, 0, 0);
    acc[1][1] = __builtin_amdgcn_mfma_f32_16x16x32_bf16(a1, b1, acc[1][1], 0, 0, 0);
  }
#pragma unroll
  for (int tm = 0; tm < 2; tm++)
#pragma unroll
    for (int tn = 0; tn < 2; tn++)
#pragma unroll
      for (int r = 0; r < 4; r++) {
        int ml = wm + tm * 16 + lq * 4 + r;
        int nl = wn + tn * 16 + lrow;
        int gm = m0 + ml, gn = n0 + nl;
        if (gm >= M || gn >= N) continue;
        float val = acc[tm][tn][r] + bias[gn];
        if constexpr (MODE == 4) {
          Cf[(size_t)gm * N + gn] = val;
        }
      }
}

// ---- MFMA flash-style attention (unchanged) ----
#define QT 16
#define NKT 13        // ceil(197/16)
#define PJ 232        // padded j extent
__global__ __launch_bounds__(256) void attn_mfma(
    const unsigned short* __restrict__ q, const unsigned short* __restrict__ k,
    const unsigned short* __restrict__ v, unsigned short* __restrict__ out) {
  int bh = blockIdx.x, b = bh / Hn, h = bh % Hn;
  const unsigned short* qp = q + (size_t)bh * Sn * DHn;
  const unsigned short* kp = k + (size_t)bh * Sn * DHn;
  const unsigned short* vp = v + (size_t)bh * Sn * DHn;
  __shared__ unsigned short Vt[DHn][PJ];      // 64 x 232 bf16 = 29 KB
  __shared__ unsigned short Pl[4][QT][PJ];    // per-wave P,   = 29 KB
  int t = threadIdx.x, lane = t & 63, wid = t >> 6;
  int col = lane & 15, quad = lane >> 4;

  for (int i = t; i < Sn * DHn; i += 256) {
    int j = i >> 6, d = i & 63;
    Vt[d][j] = vp[i];
  }
  for (int i = t; i < DHn * (PJ - Sn); i += 256) {
    int d = i / (PJ - Sn), j = Sn + i % (PJ - Sn);
    Vt[d][j] = 0;
  }
  for (int i = lane; i < QT * (PJ - NKT * 16); i += 64) {
    int r = i / (PJ - NKT * 16), c = NKT * 16 + i % (PJ - NKT * 16);
    Pl[wid][r][c] = 0;
  }
  __syncthreads();

  for (int qt = wid; qt < NKT; qt += 4) {
    int q0 = qt * QT;
    int qrow = q0 + col;
    int qc = (qrow < Sn) ? qrow : (Sn - 1);
    short8 qa0 = *(const short8*)(qp + (size_t)qc * DHn + quad * 8);
    short8 qa1 = *(const short8*)(qp + (size_t)qc * DHn + 32 + quad * 8);

    f32x4 sc[NKT];
    for (int kt = 0; kt < NKT; kt++) {
      int krow = kt * QT + col;
      int kc = (krow < Sn) ? krow : (Sn - 1);
      short8 kb0 = *(const short8*)(kp + (size_t)kc * DHn + quad * 8);
      short8 kb1 = *(const short8*)(kp + (size_t)kc * DHn + 32 + quad * 8);
      f32x4 c = {};
      c = __builtin_amdgcn_mfma_f32_16x16x32_bf16(qa0, kb0, c, 0, 0, 0);
      c = __builtin_amdgcn_mfma_f32_16x16x32_bf16(qa1, kb1, c, 0, 0, 0);
      if (krow >= Sn)
        for (int r = 0; r < 4; r++) c[r] = -1e30f;
      sc[kt] = c;
    }

    for (int r = 0; r < 4; r++) {
      float m = -1e30f;
      for (int kt = 0; kt < NKT; kt++) m = fmaxf(m, sc[kt][r]);
      for (int off = 1; off < 16; off <<= 1) m = fmaxf(m, __shfl_xor(m, off, 64));
      float s = 0.f;
      for (int kt = 0; kt < NKT; kt++) {
        float e = __expf((sc[kt][r] - m) * 0.125f);
        sc[kt][r] = e;
        s += e;
      }
      for (int off = 1; off < 16; off <<= 1) s += __shfl_xor(s, off, 64);
      float inv = 1.f / s;
      int row = quad * 4 + r;
      for (int kt = 0; kt < NKT; kt++)
        Pl[wid][row][kt * 16 + col] = f2bf(sc[kt][r] * inv);
    }

    f32x4 o[4] = {};
    for (int jc = 0; jc < 7; jc++) {
      short8 pa = *(const short8*)(&Pl[wid][col][jc * 32 + quad * 8]);
      for (int dt = 0; dt < 4; dt++) {
        short8 vb = *(const short8*)(&Vt[dt * 16 + col][jc * 32 + quad * 8]);
        o[dt] = __builtin_amdgcn_mfma_f32_16x16x32_bf16(pa, vb, o[dt], 0, 0, 0);
      }
    }

    for (int dt = 0; dt < 4; dt++)
      for (int r = 0; r < 4; r++) {
        int qq = q0 + quad * 4 + r;
        if (qq < Sn)
          out[((size_t)b * Sn + qq) * Dn + h * DHn + dt * 16 + col] =
              f2bf(o[dt][r]);
      }
  }
}

extern "C" void kernel_launch(void* const* d_in, const int* in_sizes, int n_in,
                              void* d_out, int out_size, void* d_ws, size_t ws_size,
                              hipStream_t stream) {
  const float* X       = (const float*)d_in[0];
  const float* patch_w = (const float*)d_in[1];
  const float* patch_b = (const float*)d_in[2];
  const float* cls_tok = (const float*)d_in[3];
  const float* pos_emb = (const float*)d_in[4];
  const float* ln1_g = (const float*)d_in[5];
  const float* ln1_b = (const float*)d_in[6];
  const float* Wq = (const float*)d_in[7];
  const float* bq = (const float*)d_in[8];
  const float* Wk = (const float*)d_in[9];
  const float* bk = (const float*)d_in[10];
  const float* Wv = (const float*)d_in[11];
  const float* bv = (const float*)d_in[12];
  const float* Wo = (const float*)d_in[13];
  const float* bo = (const float*)d_in[14];
  const float* ln2_g = (const float*)d_in[15];
  const float* ln2_b = (const float*)d_in[16];
  const float* Wf1 = (const float*)d_in[17];
  const float* bf1 = (const float*)d_in[18];
  const float* Wf2 = (const float*)d_in[19];
  const float* bf2 = (const float*)d_in[20];
  const float* lnf_g = (const float*)d_in[21];
  const float* lnf_b = (const float*)d_in[22];
  const float* head_w = (const float*)d_in[23];
  const float* head_b = (const float*)d_in[24];
  float* out = (float*)d_out;

  char* base = (char*)d_ws;
  size_t off = 0;
  auto alloc = [&](size_t bytes) -> void* {
    void* p = base + off;
    off += (bytes + 255) & ~(size_t)255;
    return p;
  };
  // NOTE: wq_t/wk_t/wv_t must stay consecutive (fused QKV Bt = [2304][768]);
  // qb/kb/vb must stay consecutive with MPAD*Dn stride (fused QKV epilogue).
  unsigned short* wq_t  = (unsigned short*)alloc((size_t)Dn * Dn * 2);
  unsigned short* wk_t  = (unsigned short*)alloc((size_t)Dn * Dn * 2);
  unsigned short* wv_t  = (unsigned short*)alloc((size_t)Dn * Dn * 2);
  unsigned short* wo_t  = (unsigned short*)alloc((size_t)Dn * Dn * 2);
  unsigned short* wf1_t = (unsigned short*)alloc((size_t)Dn * Fn * 2);
  unsigned short* wf2_t = (unsigned short*)alloc((size_t)Dn * Fn * 2);
  unsigned short* pw_bf = (unsigned short*)alloc((size_t)Dn * Dn * 2);
  unsigned short* hw_t  = (unsigned short*)alloc((size_t)NCLSn * Dn * 2);
  unsigned short* im2c  = (unsigned short*)alloc((size_t)MPAD * Dn * 2);
  float*          x     = (float*)alloc((size_t)MTOK * Dn * 4);
  unsigned short* h_bf  = (unsigned short*)alloc((size_t)MPAD * Dn * 2);
  unsigned short* qb    = (unsigned short*)alloc((size_t)MPAD * Dn * 2);
  unsigned short* kb    = (unsigned short*)alloc((size_t)MPAD * Dn * 2);
  unsigned short* vb    = (unsigned short*)alloc((size_t)MPAD * Dn * 2);
  unsigned short* atob  = (unsigned short*)alloc((size_t)MPAD * Dn * 2);
  unsigned short* gel   = (unsigned short*)alloc((size_t)MPAD * Fn * 2);
  unsigned short* clsb  = (unsigned short*)alloc((size_t)Bn * Dn * 2);
  float*          bqkv  = (float*)alloc((size_t)Ln * 3 * Dn * 4);
  (void)in_sizes; (void)n_in; (void)out_size;

  // optional split-K partial planes (4 x [MTOK][Dn] fp32 = 77.5 MB)
  const size_t SZ_PART = (size_t)4 * MTOK * Dn * 4;
  float* part = nullptr;
  if (off + SZ_PART + 4096 <= ws_size) part = (float*)alloc(SZ_PART);
  // optional hoisted all-layer transposed weights (~170 MB)
  const size_t SZ_QKV = (size_t)Ln * 3 * Dn * Dn * 2;
  const size_t SZ_WO  = (size_t)Ln * Dn * Dn * 2;
  const size_t SZ_WF  = (size_t)Ln * Dn * Fn * 2;
  unsigned short *wqkv_all = nullptr, *wo_all = nullptr,
                 *wf1_all = nullptr, *wf2_all = nullptr;
  if (off + SZ_QKV + SZ_WO + 2 * SZ_WF + 8192 <= ws_size) {
    wqkv_all = (unsigned short*)alloc(SZ_QKV);
    wo_all   = (unsigned short*)alloc(SZ_WO);
    wf1_all  = (unsigned short*)alloc(SZ_WF);
    wf2_all  = (unsigned short*)alloc(SZ_WF);
  }
  const bool sk = part != nullptr;
  const bool hoist = wqkv_all != nullptr;

  dim3 tb(32, 8);
  auto tgrid = [](int rows, int cols) { return dim3((cols + 31) / 32, (rows + 31) / 32); };
  auto g128 = [](int M, int N, int ks) {
    return dim3((unsigned)(((M + 127) / 128) * ((N + 127) / 128) * ks));
  };

  // prologue
  cast_bf<<<(Dn * Dn + 255) / 256, 256, 0, stream>>>(patch_w, pw_bf, Dn * Dn);
  transpose_cast<<<tgrid(Dn, NCLSn), tb, 0, stream>>>(head_w, hw_t, Dn, NCLSn);
  pack_qkv_bias<<<(Ln * 3 * Dn + 255) / 256, 256, 0, stream>>>(bq, bk, bv, bqkv);
  im2col_patches<<<(Bn * NPATCH * Dn + 255) / 256, 256, 0, stream>>>(X, im2c);
  init_cls<<<(Bn * Dn + 255) / 256, 256, 0, stream>>>(cls_tok, pos_emb, x);
  gemm128<3><<<g128(Bn * NPATCH, Dn, 1), 256, 0, stream>>>(
      im2c, pw_bf, patch_b, pos_emb, x, nullptr, Bn * NPATCH, Dn, Dn, Dn, 1, Dn / 128);

  if (hoist) {  // all-layer weight transposes, batched over z = layer
    dim3 z88(24, 24, Ln);
    transpose_cast_b<<<z88, tb, 0, stream>>>(
        Wq, wqkv_all, Dn, Dn, (size_t)Dn * Dn, (size_t)3 * Dn * Dn, 0);
    transpose_cast_b<<<z88, tb, 0, stream>>>(
        Wk, wqkv_all, Dn, Dn, (size_t)Dn * Dn, (size_t)3 * Dn * Dn, Dn);
    transpose_cast_b<<<z88, tb, 0, stream>>>(
        Wv, wqkv_all, Dn, Dn, (size_t)Dn * Dn, (size_t)3 * Dn * Dn, 2 * Dn);
    transpose_cast_b<<<z88, tb, 0, stream>>>(
        Wo, wo_all, Dn, Dn, (size_t)Dn * Dn, (size_t)Dn * Dn, 0);
    transpose_cast_b<<<dim3(96, 24, Ln), tb, 0, stream>>>(
        Wf1, wf1_all, Dn, Fn, (size_t)Dn * Fn, (size_t)Fn * Dn, 0);
    transpose_cast_b<<<dim3(24, 96, Ln), tb, 0, stream>>>(
        Wf2, wf2_all, Fn, Dn, (size_t)Fn * Dn, (size_t)Dn * Fn, 0);
  }

  for (int l = 0; l < Ln; l++) {
    const size_t wo_off = (size_t)l * Dn * Dn;
    const size_t wf_off = (size_t)l * Dn * Fn;
    const unsigned short* wqkv_l = hoist ? wqkv_all + (size_t)l * 3 * Dn * Dn : wq_t;
    const unsigned short* wo_l   = hoist ? wo_all + wo_off : wo_t;
    const unsigned short* wf1_l  = hoist ? wf1_all + wf_off : wf1_t;
    const unsigned short* wf2_l  = hoist ? wf2_all + wf_off : wf2_t;
    if (!hoist) {
      transpose_cast<<<tgrid(Dn, Dn), tb, 0, stream>>>(Wq + wo_off, wq_t, Dn, Dn);
      transpose_cast<<<tgrid(Dn, Dn), tb, 0, stream>>>(Wk + wo_off, wk_t, Dn, Dn);
      transpose_cast<<<tgrid(Dn, Dn), tb, 0, stream>>>(Wv + wo_off, wv_t, Dn, Dn);
      transpose_cast<<<tgrid(Dn, Dn), tb, 0, stream>>>(Wo + wo_off, wo_t, Dn, Dn);
      transpose_cast<<<tgrid(Dn, Fn), tb, 0, stream>>>(Wf1 + wf_off, wf1_t, Dn, Fn);
      transpose_cast<<<tgrid(Fn, Dn), tb, 0, stream>>>(Wf2 + wf_off, wf2_t, Fn, Dn);
    }

    layernorm_k<<<MTOK, 256, 0, stream>>>(x, Dn, ln1_g + (size_t)l * Dn,
                                          ln1_b + (size_t)l * Dn, h_bf);
    // fused QKV: Bt = [wq|wk|wv]^T contiguous = [2304][768]
    gemm128<5><<<g128(MTOK, 3 * Dn, 1), 256, 0, stream>>>(
        h_bf, wqkv_l, bqkv + (size_t)l * 3 * Dn, nullptr, nullptr, qb,
        MTOK, 3 * Dn, Dn, Dn, 1, 3 * Dn / 128);
    attn_mfma<<<Bn * Hn, 256, 0, stream>>>(qb, kb, vb, atob);
    if (sk) {  // Wo projection, split-K x2 (grid 300 -> 600 blocks)
      gemm128<6><<<g128(MTOK, Dn, 2), 256, 0, stream>>>(
          atob, wo_l, nullptr, nullptr, part, nullptr,
          MTOK, Dn, Dn / 2, Dn, 2, Dn / 128);
      splitk_reduce<<<(MTOK * Dn / 4 + 255) / 256, 256, 0, stream>>>(
          part, bo + (size_t)l * Dn, x, Dn, 2);
    } else {
      gemm128<1><<<g128(MTOK, Dn, 1), 256, 0, stream>>>(
          atob, wo_l, bo + (size_t)l * Dn, x, x, nullptr, MTOK, Dn, Dn, Dn, 1, Dn / 128);
    }
    layernorm_k<<<MTOK, 256, 0, stream>>>(x, Dn, ln2_g + (size_t)l * Dn,
                                          ln2_b + (size_t)l * Dn, h_bf);
    gemm128<2><<<g128(MTOK, Fn, 1), 256, 0, stream>>>(
        h_bf, wf1_l, bf1 + (size_t)l * Fn, nullptr, nullptr, gel,
        MTOK, Fn, Dn, Dn, 1, Fn / 128);
    if (sk) {  // FF2, split-K x4 (grid 300 -> 1200 blocks)
      gemm128<6><<<g128(MTOK, Dn, 4), 256, 0, stream>>>(
          gel, wf2_l, nullptr, nullptr, part, nullptr,
          MTOK, Dn, Fn / 4, Fn, 4, Dn / 128);
      splitk_reduce<<<(MTOK * Dn / 4 + 255) / 256, 256, 0, stream>>>(
          part, bf2 + (size_t)l * Dn, x, Dn, 4);
    } else {
      gemm128<1><<<g128(MTOK, Dn, 1), 256, 0, stream>>>(
          gel, wf2_l, bf2 + (size_t)l * Dn, x, x, nullptr, MTOK, Dn, Fn, Fn, 1, Dn / 128);
    }
  }

  layernorm_k<<<Bn, 256, 0, stream>>>(x, Sn * Dn, lnf_g, lnf_b, clsb);
  gemm64<4><<<dim3(1, (NCLSn + 63) / 64), 256, 0, stream>>>(
      clsb, hw_t, head_b, nullptr, out, nullptr, Bn, NCLSn, Dn);
}